// Round 2
// baseline (2407.462 us; speedup 1.0000x reference)
//
#include <hip/hip_runtime.h>
#include <hip/hip_bf16.h>

typedef unsigned short US;
typedef short short8 __attribute__((ext_vector_type(8)));
typedef float f32x4 __attribute__((ext_vector_type(4)));

__device__ __forceinline__ float bf2f(US u){ union{unsigned int i; float f;}x; x.i=((unsigned int)u)<<16; return x.f; }
__device__ __forceinline__ US f2bf(float f){ union{float f; unsigned int i;}x; x.f=f; return (US)((x.i + 0x7fffu + ((x.i>>16)&1u))>>16); }

__device__ __forceinline__ float wredsum(float v){
    #pragma unroll
    for (int off=1; off<64; off<<=1) v += __shfl_xor(v, off);
    return v;
}

// ---------------- small prep kernels ----------------

__global__ void k_copy(const float* __restrict__ x, float* __restrict__ xf, int n){
    int i = blockIdx.x*256+threadIdx.x;
    if (i < n) xf[i] = x[i];
}

__global__ void k_f2b(const float* __restrict__ w, US* __restrict__ o, int n){
    int i = blockIdx.x*256+threadIdx.x;
    if (i < n) o[i] = f2bf(w[i]);
}

// detect whether is_any_modality is int32 (values 0/1) or byte-packed
__global__ void k_detect(const int* __restrict__ p, int* flag){
    __shared__ int f;
    if (threadIdx.x==0) f=0;
    __syncthreads();
    int bad=0;
    for (int i=threadIdx.x;i<1024;i+=256) if (((unsigned)p[i])>1u) bad=1;
    if (bad) atomicOr(&f,1);
    __syncthreads();
    if (threadIdx.x==0) *flag=f;
}
__global__ void k_mod(const int* __restrict__ p, const int* __restrict__ flag, unsigned char* __restrict__ mod){
    int t = blockIdx.x*256+threadIdx.x;
    if (t<4096){
        int v = (*flag) ? (int)(((const unsigned char*)p)[t]) : p[t];
        mod[t] = v?1:0;
    }
}

__global__ void k_padw1(const float* __restrict__ w, US* __restrict__ wp){ // (4,512,2730)->(4,512,2752) bf16
    int i = blockIdx.x*256+threadIdx.x;
    if (i >= 4*512*2752) return;
    int n = i % 2752; int lk = i / 2752;
    wp[i] = (n<2730) ? f2bf(w[lk*2730 + n]) : (US)0;
}
__global__ void k_padb1(const float* __restrict__ b, float* __restrict__ bp){
    int i = blockIdx.x*256+threadIdx.x;
    if (i >= 4*2752) return;
    int n = i % 2752; int l = i / 2752;
    bp[i] = (n<2730) ? b[l*2730+n] : 0.f;
}
__global__ void k_padw2(const float* __restrict__ w, US* __restrict__ wp){ // (4,1365,512)->(4,1376,512) bf16
    int i = blockIdx.x*256+threadIdx.x;
    if (i >= 4*1376*512) return;
    int n = i % 512; int r = i / 512; int k = r % 1376; int l = r / 1376;
    wp[i] = (k<1365) ? f2bf(w[(l*1365+k)*512 + n]) : (US)0;
}

__global__ void k_femb(const float* __restrict__ times, const float* __restrict__ fw, float* __restrict__ femb){
    int i = blockIdx.x*256 + threadIdx.x;
    if (i >= 2*513) return;
    int b = i / 513, k = i % 513;
    float t = times[b];
    float val;
    if (k == 0) val = t;
    else if (k <= 256) val = sinf(t * fw[k-1] * 6.2831853071795865f);
    else val = cosf(t * fw[k-257] * 6.2831853071795865f);
    femb[i] = val;
}

__global__ void k_cond(const float* __restrict__ femb, const float* __restrict__ time_w,
                       const float* __restrict__ time_b, float* __restrict__ cond){
    int gid = blockIdx.x*256 + threadIdx.x; // < 4096
    int b = gid >> 11, j = gid & 2047;
    const float* fr = femb + b*513;
    float acc = 0.f;
    #pragma unroll 8
    for (int k = 0; k < 513; ++k) acc += fr[k]*time_w[k*2048 + j];
    acc += time_b[j];
    cond[gid] = acc / (1.f + expf(-acc));
}

__global__ void k_film(const float* __restrict__ cond, const float* __restrict__ film_w,
                       const float* __restrict__ film_b, const float* __restrict__ zero_w,
                       const float* __restrict__ zero_b,
                       float* __restrict__ gamma, float* __restrict__ beta, float* __restrict__ gate){
    int gid = blockIdx.x*256 + threadIdx.x; // < 3072
    int b = gid / 1536, c = gid % 1536;
    const float* cr = cond + b*2048;
    if (c < 1024) {
        float acc = 0.f;
        #pragma unroll 8
        for (int k = 0; k < 2048; ++k) acc += cr[k]*film_w[k*1024 + c];
        acc += film_b[c];
        if (c < 512) gamma[b*512+c] = acc; else beta[b*512 + c-512] = acc;
    } else {
        int j = c - 1024;
        float acc = 0.f;
        #pragma unroll 8
        for (int k = 0; k < 2048; ++k) acc += cr[k]*zero_w[k*512 + j];
        acc += zero_b[j];
        gate[b*512+j] = 1.f/(1.f+expf(-acc));
    }
}

// fused layernorm -> FiLM/static modulation -> rmsnorm ; one wave per token
__global__ __launch_bounds__(256) void k_normmod(
    const float* __restrict__ X, const float* __restrict__ gamma, const float* __restrict__ beta,
    const float* __restrict__ lng, const float* __restrict__ ng,
    const unsigned char* __restrict__ modv, US* __restrict__ Y)
{
    int token = blockIdx.x*4 + (threadIdx.x>>6);
    int lane = threadIdx.x & 63;
    int b = token >> 11;
    const float* xr = X + ((size_t)token<<9);
    float v[8], s=0.f;
    #pragma unroll
    for (int j=0;j<8;++j){ v[j]=xr[(j<<6)+lane]; s+=v[j]; }
    s = wredsum(s);
    float mu = s*(1.f/512.f);
    float vs = 0.f;
    #pragma unroll
    for (int j=0;j<8;++j){ float d=v[j]-mu; vs+=d*d; }
    vs = wredsum(vs);
    float rsig = rsqrtf(vs*(1.f/512.f)+1e-5f);
    int md = modv[token];
    float xin[8], ss=0.f;
    #pragma unroll
    for (int j=0;j<8;++j){
        int d = (j<<6)+lane;
        float hn = (v[j]-mu)*rsig;
        float xi = md ? hn*(gamma[(b<<9)+d]+1.f)+beta[(b<<9)+d] : hn*(lng[d]+1.f);
        xin[j]=xi; ss+=xi*xi;
    }
    ss = wredsum(ss);
    float fac = 22.62741699796952f / fmaxf(sqrtf(ss), 1e-12f);
    #pragma unroll
    for (int j=0;j<8;++j){
        int d=(j<<6)+lane;
        Y[((size_t)token<<9)+d] = f2bf(xin[j]*fac*(ng[d]+1.f));
    }
}

__global__ __launch_bounds__(256) void k_final(const float* __restrict__ X, const float* __restrict__ g, float* __restrict__ out){
    int token = blockIdx.x*4 + (threadIdx.x>>6);
    int lane = threadIdx.x & 63;
    const float* xr = X + ((size_t)token<<9);
    float v[8], ss=0.f;
    #pragma unroll
    for (int j=0;j<8;++j){ v[j]=xr[(j<<6)+lane]; ss+=v[j]*v[j]; }
    ss=wredsum(ss);
    float fac = 22.62741699796952f / fmaxf(sqrtf(ss),1e-12f);
    #pragma unroll
    for (int j=0;j<8;++j){
        int d=(j<<6)+lane;
        out[((size_t)token<<9)+d] = v[j]*fac*(g[d]+1.f);
    }
}

__global__ void k_act(const US* __restrict__ u, US* __restrict__ act){
    int idx = blockIdx.x*256+threadIdx.x;
    if (idx >= 4096*1376) return;
    int t = idx / 1376, c = idx % 1376;
    float val = 0.f;
    if (c < 1365) {
        float a = bf2f(u[t*2752 + c]);
        float g = bf2f(u[t*2752 + 1365 + c]);
        val = 0.5f*g*(1.f+erff(g*0.70710678118f)) * a;
    }
    act[idx] = f2bf(val);
}

// ---------------- MFMA GEMM: C(MxN) = A(MxK) @ B(KxN), tiles 64x64x32, A/B bf16 ----------------
// EPI 0: store bf16 C. EPI 1: +bias(f32), store bf16 C.
// EPI 2: gate/scale select + residual add into fp32 X (N==512). EPI 3: +bias then as EPI 2.
template<int EPI>
__global__ __launch_bounds__(256) void k_gemm(
    const US* __restrict__ A, const US* __restrict__ Bm, US* __restrict__ C,
    const float* __restrict__ bias, float* __restrict__ X,
    const float* __restrict__ gate, const float* __restrict__ scale,
    const unsigned char* __restrict__ modv, int M, int N, int K)
{
    __shared__ US As[64*40];   // [row][k] row-major, pad 32->40
    __shared__ US Bs[64*40];   // transposed: [n][k]
    int tid = threadIdx.x;
    int wave = tid>>6, lane = tid&63, quad = lane>>4, l15 = lane&15;
    int m0 = blockIdx.y<<6, n0 = blockIdx.x<<6;
    f32x4 acc[4];
    #pragma unroll
    for (int nb=0;nb<4;++nb) acc[nb] = (f32x4){0.f,0.f,0.f,0.f};
    int arow = tid>>2, ac8 = (tid&3)<<3;
    int bn = tid&63, bk8 = (tid>>6)<<3;
    const US* Aptr = A + (size_t)(m0+arow)*K + ac8;
    const US* Bptr = Bm + n0 + bn;
    for (int k0=0;k0<K;k0+=32){
        __syncthreads();
        *(uint4*)&As[arow*40+ac8] = *(const uint4*)(Aptr + k0);
        {
            const US* bp = Bptr + (size_t)(k0+bk8)*N;
            unsigned int u0 = (unsigned int)bp[0]           | ((unsigned int)bp[(size_t)N]<<16);
            unsigned int u1 = (unsigned int)bp[2*(size_t)N] | ((unsigned int)bp[3*(size_t)N]<<16);
            unsigned int u2 = (unsigned int)bp[4*(size_t)N] | ((unsigned int)bp[5*(size_t)N]<<16);
            unsigned int u3 = (unsigned int)bp[6*(size_t)N] | ((unsigned int)bp[7*(size_t)N]<<16);
            uint4 wv; wv.x=u0; wv.y=u1; wv.z=u2; wv.w=u3;
            *(uint4*)&Bs[bn*40+bk8] = wv;
        }
        __syncthreads();
        short8 af = *(const short8*)&As[(wave*16+l15)*40 + (quad<<3)];
        #pragma unroll
        for (int nb=0;nb<4;++nb){
            short8 bf = *(const short8*)&Bs[((nb<<4)+l15)*40 + (quad<<3)];
            acc[nb] = __builtin_amdgcn_mfma_f32_16x16x32_bf16(af, bf, acc[nb], 0,0,0);
        }
    }
    #pragma unroll
    for (int nb=0;nb<4;++nb){
        int col = n0 + (nb<<4) + l15;
        #pragma unroll
        for (int r=0;r<4;++r){
            int row = m0 + wave*16 + (quad<<2) + r;
            float v = acc[nb][r];
            if (EPI==1 || EPI==3) v += bias[col];
            if (EPI<=1){
                C[(size_t)row*N + col] = f2bf(v);
            } else {
                float o = modv[row] ? v*gate[((row>>11)<<9) + col] : v*scale[col];
                X[((size_t)row<<9) + col] += o;
            }
        }
    }
}

// ---------------- MFMA flash attention, causal, softcap 50 ----------------
__global__ __launch_bounds__(256) void k_attn(const US* __restrict__ qkv, US* __restrict__ O)
{
    int blk = blockIdx.x;          // 512 blocks
    int rb = blk & 31, bh = blk >> 5;
    int b = bh >> 3, h = bh & 7;
    int tid = threadIdx.x, wave = tid>>6, lane = tid&63, quad = lane>>4, l15 = lane&15;
    __shared__ US Ks[64*72];       // [key][d]
    __shared__ US Vt[64*72];       // [d][key]
    __shared__ US Ps[4][16*72];    // per-wave P relayout [row][key]
    int qrow0 = (rb<<6) + (wave<<4);
    const US* qbase = qkv + (size_t)(b*2048 + qrow0 + l15)*1536 + h*64 + (quad<<3);
    short8 qf0 = *(const short8*)qbase;
    short8 qf1 = *(const short8*)(qbase + 32);
    f32x4 Oa[4];
    #pragma unroll
    for (int nb=0;nb<4;++nb) Oa[nb]=(f32x4){0.f,0.f,0.f,0.f};
    float m_r[4], l_r[4];
    #pragma unroll
    for (int r=0;r<4;++r){ m_r[r]=-1e30f; l_r[r]=0.f; }
    int nch = rb+1;
    for (int c=0;c<nch;++c){
        int j0 = c<<6;
        __syncthreads();
        #pragma unroll
        for (int it=0;it<2;++it){
            int g = tid + (it<<8);
            int key = g>>3, d8 = (g&7)<<3;
            *(uint4*)&Ks[key*72+d8] = *(const uint4*)(qkv + (size_t)(b*2048 + j0 + key)*1536 + 512 + h*64 + d8);
        }
        #pragma unroll
        for (int it=0;it<16;++it){
            int e = tid + (it<<8);
            int key = e>>6, d = e&63;
            Vt[d*72+key] = qkv[(size_t)(b*2048 + j0 + key)*1536 + 1024 + h*64 + d];
        }
        __syncthreads();
        f32x4 s[4];
        #pragma unroll
        for (int nb=0;nb<4;++nb){
            s[nb]=(f32x4){0.f,0.f,0.f,0.f};
            short8 kf0 = *(const short8*)&Ks[((nb<<4)+l15)*72 + (quad<<3)];
            short8 kf1 = *(const short8*)&Ks[((nb<<4)+l15)*72 + 32 + (quad<<3)];
            s[nb] = __builtin_amdgcn_mfma_f32_16x16x32_bf16(qf0, kf0, s[nb],0,0,0);
            s[nb] = __builtin_amdgcn_mfma_f32_16x16x32_bf16(qf1, kf1, s[nb],0,0,0);
        }
        float sims[4][4], mx[4];
        #pragma unroll
        for (int r=0;r<4;++r) mx[r]=-1e30f;
        #pragma unroll
        for (int nb=0;nb<4;++nb){
            int key = j0 + (nb<<4) + l15;
            #pragma unroll
            for (int r=0;r<4;++r){
                // scale 1/sqrt(64)=0.125 folded: tanh(raw*0.125/50)*50
                float sim = 50.f*tanhf(s[nb][r]*0.0025f);
                int rowg = qrow0 + (quad<<2) + r;
                if (key > rowg) sim = -1e30f;
                sims[nb][r]=sim;
                mx[r]=fmaxf(mx[r],sim);
            }
        }
        #pragma unroll
        for (int off=1; off<16; off<<=1){
            #pragma unroll
            for (int r=0;r<4;++r) mx[r]=fmaxf(mx[r], __shfl_xor(mx[r],off));
        }
        float alpha[4], sum[4];
        #pragma unroll
        for (int r=0;r<4;++r){
            float mn = fmaxf(m_r[r], mx[r]);
            alpha[r]=expf(m_r[r]-mn);
            m_r[r]=mn; sum[r]=0.f;
        }
        #pragma unroll
        for (int nb=0;nb<4;++nb){
            #pragma unroll
            for (int r=0;r<4;++r){
                float p = expf(sims[nb][r]-m_r[r]);
                sims[nb][r]=p; sum[r]+=p;
            }
        }
        #pragma unroll
        for (int off=1; off<16; off<<=1){
            #pragma unroll
            for (int r=0;r<4;++r) sum[r] += __shfl_xor(sum[r],off);
        }
        #pragma unroll
        for (int r=0;r<4;++r) l_r[r]=l_r[r]*alpha[r]+sum[r];
        #pragma unroll
        for (int nb=0;nb<4;++nb){
            #pragma unroll
            for (int r=0;r<4;++r) Oa[nb][r]*=alpha[r];
        }
        US* ps = &Ps[wave][0];
        #pragma unroll
        for (int nb=0;nb<4;++nb){
            #pragma unroll
            for (int r=0;r<4;++r)
                ps[((quad<<2)+r)*72 + (nb<<4)+l15] = f2bf(sims[nb][r]);
        }
        short8 pf0 = *(const short8*)&ps[l15*72 + (quad<<3)];
        short8 pf1 = *(const short8*)&ps[l15*72 + 32 + (quad<<3)];
        #pragma unroll
        for (int nb=0;nb<4;++nb){
            short8 vf0 = *(const short8*)&Vt[((nb<<4)+l15)*72 + (quad<<3)];
            short8 vf1 = *(const short8*)&Vt[((nb<<4)+l15)*72 + 32 + (quad<<3)];
            Oa[nb] = __builtin_amdgcn_mfma_f32_16x16x32_bf16(pf0, vf0, Oa[nb],0,0,0);
            Oa[nb] = __builtin_amdgcn_mfma_f32_16x16x32_bf16(pf1, vf1, Oa[nb],0,0,0);
        }
    }
    #pragma unroll
    for (int nb=0;nb<4;++nb){
        #pragma unroll
        for (int r=0;r<4;++r){
            int rowg = qrow0 + (quad<<2) + r;
            O[(size_t)(b*2048+rowg)*512 + h*64 + (nb<<4) + l15] = f2bf(Oa[nb][r]/fmaxf(l_r[r],1e-20f));
        }
    }
}

// ---------------- launcher ----------------
extern "C" void kernel_launch(void* const* d_in, const int* in_sizes, int n_in,
                              void* d_out, int out_size, void* d_ws, size_t ws_size,
                              hipStream_t stream)
{
    (void)in_sizes; (void)n_in; (void)out_size; (void)ws_size;
    const float* x        = (const float*)d_in[0];
    const float* times    = (const float*)d_in[1];
    const int*   mod_raw  = (const int*)d_in[3];   // attn_mask (d_in[2]) = causal tril, hardcoded
    const float* fourier  = (const float*)d_in[4];
    const float* time_w   = (const float*)d_in[5];
    const float* time_b   = (const float*)d_in[6];
    const float* aw_ln_g  = (const float*)d_in[7];
    const float* aw_scale = (const float*)d_in[8];
    const float* aw_film_w= (const float*)d_in[9];
    const float* aw_film_b= (const float*)d_in[10];
    const float* aw_zero_w= (const float*)d_in[11];
    const float* aw_zero_b= (const float*)d_in[12];
    const float* attn_norm_g=(const float*)d_in[13];
    const float* qkv_w    = (const float*)d_in[14];
    const float* out_w    = (const float*)d_in[15];
    const float* fw_ln_g  = (const float*)d_in[16];
    const float* fw_scale = (const float*)d_in[17];
    const float* fw_film_w= (const float*)d_in[18];
    const float* fw_film_b= (const float*)d_in[19];
    const float* fw_zero_w= (const float*)d_in[20];
    const float* fw_zero_b= (const float*)d_in[21];
    const float* ff_norm_g= (const float*)d_in[22];
    const float* ff_w1    = (const float*)d_in[23];
    const float* ff_b1    = (const float*)d_in[24];
    const float* ff_w2    = (const float*)d_in[25];
    const float* ff_b2    = (const float*)d_in[26];
    const float* final_g  = (const float*)d_in[27];

    char* ws = (char*)d_ws;
    size_t off = 0;
    auto alloc = [&](size_t bytes)->char*{ char* p = ws+off; off += (bytes + 255) & ~(size_t)255; return p; };
    float* Xf   = (float*)alloc(4096ull*512*4);
    US* Y       = (US*)alloc(4096ull*512*2);
    US* QKV     = (US*)alloc(4096ull*1536*2);
    US* Ob      = (US*)alloc(4096ull*512*2);
    US* U       = (US*)alloc(4096ull*2752*2);
    US* ACT     = (US*)alloc(4096ull*1376*2);
    US* QW      = (US*)alloc(4ull*512*1536*2);
    US* OW      = (US*)alloc(4ull*512*512*2);
    US* W1P     = (US*)alloc(4ull*512*2752*2);
    float* B1P  = (float*)alloc(4ull*2752*4);
    US* W2P     = (US*)alloc(4ull*1376*512*2);
    float* FEMB = (float*)alloc(2*513*4);
    float* COND = (float*)alloc(2*2048*4);
    float* GAM  = (float*)alloc(2*512*4);
    float* BET  = (float*)alloc(2*512*4);
    float* GATE = (float*)alloc(2*512*4);
    unsigned char* MOD = (unsigned char*)alloc(4096);
    int* FLAG   = (int*)alloc(256);

    k_copy<<<8192,256,0,stream>>>(x, Xf, 4096*512);
    k_detect<<<1,256,0,stream>>>(mod_raw, FLAG);
    k_mod<<<16,256,0,stream>>>(mod_raw, FLAG, MOD);
    k_f2b<<<(4*512*1536+255)/256,256,0,stream>>>(qkv_w, QW, 4*512*1536);
    k_f2b<<<(4*512*512+255)/256,256,0,stream>>>(out_w, OW, 4*512*512);
    k_padw1<<<(4*512*2752+255)/256,256,0,stream>>>(ff_w1, W1P);
    k_padb1<<<(4*2752+255)/256,256,0,stream>>>(ff_b1, B1P);
    k_padw2<<<(4*1376*512+255)/256,256,0,stream>>>(ff_w2, W2P);
    k_femb<<<5,256,0,stream>>>(times, fourier, FEMB);
    k_cond<<<16,256,0,stream>>>(FEMB, time_w, time_b, COND);

    for (int l=0;l<4;++l){
        // ---- attention block ----
        k_film<<<12,256,0,stream>>>(COND, aw_film_w + (size_t)l*2048*1024, aw_film_b + l*1024,
                                    aw_zero_w + (size_t)l*2048*512, aw_zero_b + l*512, GAM,BET,GATE);
        k_normmod<<<1024,256,0,stream>>>(Xf, GAM, BET, aw_ln_g + l*512, attn_norm_g + l*512, MOD, Y);
        k_gemm<0><<<dim3(1536/64,64),256,0,stream>>>(Y, QW + (size_t)l*512*1536, QKV,
                    nullptr, nullptr, nullptr, nullptr, nullptr, 4096,1536,512);
        k_attn<<<512,256,0,stream>>>(QKV, Ob);
        k_gemm<2><<<dim3(512/64,64),256,0,stream>>>(Ob, OW + (size_t)l*512*512, nullptr,
                    nullptr, Xf, GATE, aw_scale + l*512, MOD, 4096,512,512);
        // ---- feed-forward block ----
        k_film<<<12,256,0,stream>>>(COND, fw_film_w + (size_t)l*2048*1024, fw_film_b + l*1024,
                                    fw_zero_w + (size_t)l*2048*512, fw_zero_b + l*512, GAM,BET,GATE);
        k_normmod<<<1024,256,0,stream>>>(Xf, GAM, BET, fw_ln_g + l*512, ff_norm_g + l*512, MOD, Y);
        k_gemm<1><<<dim3(2752/64,64),256,0,stream>>>(Y, W1P + (size_t)l*512*2752, U,
                    B1P + l*2752, nullptr, nullptr, nullptr, nullptr, 4096,2752,512);
        k_act<<<(4096*1376+255)/256,256,0,stream>>>(U, ACT);
        k_gemm<3><<<dim3(512/64,64),256,0,stream>>>(ACT, W2P + (size_t)l*1376*512, nullptr,
                    ff_b2 + l*512, Xf, GATE, fw_scale + l*512, MOD, 4096,512,1376);
    }
    k_final<<<1024,256,0,stream>>>(Xf, final_g, (float*)d_out);
}

// Round 3
// 1311.005 us; speedup vs baseline: 1.8363x; 1.8363x over previous
//
#include <hip/hip_runtime.h>
#include <hip/hip_bf16.h>

typedef unsigned short US;
typedef short short8 __attribute__((ext_vector_type(8)));
typedef float f32x4 __attribute__((ext_vector_type(4)));

__device__ __forceinline__ float bf2f(US u){ union{unsigned int i; float f;}x; x.i=((unsigned int)u)<<16; return x.f; }
__device__ __forceinline__ US f2bf(float f){ union{float f; unsigned int i;}x; x.f=f; return (US)((x.i + 0x7fffu + ((x.i>>16)&1u))>>16); }

__device__ __forceinline__ float wredsum(float v){
    #pragma unroll
    for (int off=1; off<64; off<<=1) v += __shfl_xor(v, off);
    return v;
}

// ---------------- small prep kernels ----------------

__global__ void k_copy(const float* __restrict__ x, float* __restrict__ xf, int n){
    int i = blockIdx.x*256+threadIdx.x;
    if (i < n) xf[i] = x[i];
}

__global__ void k_f2b(const float* __restrict__ w, US* __restrict__ o, int n){
    int i = blockIdx.x*256+threadIdx.x;
    if (i < n) o[i] = f2bf(w[i]);
}

// detect whether is_any_modality is int32 (values 0/1) or byte-packed
__global__ void k_detect(const int* __restrict__ p, int* flag){
    __shared__ int f;
    if (threadIdx.x==0) f=0;
    __syncthreads();
    int bad=0;
    for (int i=threadIdx.x;i<1024;i+=256) if (((unsigned)p[i])>1u) bad=1;
    if (bad) atomicOr(&f,1);
    __syncthreads();
    if (threadIdx.x==0) *flag=f;
}
__global__ void k_mod(const int* __restrict__ p, const int* __restrict__ flag, unsigned char* __restrict__ mod){
    int t = blockIdx.x*256+threadIdx.x;
    if (t<4096){
        int v = (*flag) ? (int)(((const unsigned char*)p)[t]) : p[t];
        mod[t] = v?1:0;
    }
}

__global__ void k_padw1(const float* __restrict__ w, US* __restrict__ wp){ // (4,512,2730)->(4,512,2752) bf16
    int i = blockIdx.x*256+threadIdx.x;
    if (i >= 4*512*2752) return;
    int n = i % 2752; int lk = i / 2752;
    wp[i] = (n<2730) ? f2bf(w[lk*2730 + n]) : (US)0;
}
__global__ void k_padb1(const float* __restrict__ b, float* __restrict__ bp){
    int i = blockIdx.x*256+threadIdx.x;
    if (i >= 4*2752) return;
    int n = i % 2752; int l = i / 2752;
    bp[i] = (n<2730) ? b[l*2730+n] : 0.f;
}
__global__ void k_padw2(const float* __restrict__ w, US* __restrict__ wp){ // (4,1365,512)->(4,1376,512) bf16
    int i = blockIdx.x*256+threadIdx.x;
    if (i >= 4*1376*512) return;
    int n = i % 512; int r = i / 512; int k = r % 1376; int l = r / 1376;
    wp[i] = (k<1365) ? f2bf(w[(l*1365+k)*512 + n]) : (US)0;
}

__global__ void k_femb(const float* __restrict__ times, const float* __restrict__ fw, float* __restrict__ femb){
    int i = blockIdx.x*256 + threadIdx.x;
    if (i >= 2*513) return;
    int b = i / 513, k = i % 513;
    float t = times[b];
    float val;
    if (k == 0) val = t;
    else if (k <= 256) val = sinf(t * fw[k-1] * 6.2831853071795865f);
    else val = cosf(t * fw[k-257] * 6.2831853071795865f);
    femb[i] = val;
}

// cond matvec stage 1: 64 blocks x 4 waves; wave = (colwave, kchunk); coalesced over cols
__global__ __launch_bounds__(256) void k_cond1(const float* __restrict__ femb,
    const float* __restrict__ time_w, float* __restrict__ CACC)
{
    int wid = blockIdx.x*4 + (threadIdx.x>>6);   // 0..255
    int lane = threadIdx.x & 63;
    int kchunk = wid & 3;
    int colwave = wid >> 2;                      // 0..63
    int j = ((colwave & 31) << 6) + lane;        // 0..2047
    int b = colwave >> 5;
    int k0 = kchunk*129, k1 = k0+129; if (k1>513) k1=513;
    const float* fr = femb + b*513;
    float acc = 0.f;
    for (int k=k0;k<k1;++k) acc += fr[k]*time_w[(size_t)k*2048 + j];
    atomicAdd(&CACC[b*2048 + j], acc);
}
__global__ void k_condfin(const float* __restrict__ CACC, const float* __restrict__ time_b,
                          float* __restrict__ cond){
    int i = blockIdx.x*256+threadIdx.x;  // 4096
    if (i>=4096) return;
    float v = CACC[i] + time_b[i & 2047];
    cond[i] = v/(1.f+expf(-v));
}

// all-layer FiLM/gate matvec stage 1.
// colinst = ((lt*2)+b)*1536 + c   with lt = l*2 + t (t: 0=attn-block, 1=ff-block)
//   c in [0,1024): film (gamma/beta), c in [1024,1536): zero (gate)
// waves: 384 col-waves x 4 K-chunks = 1536 waves = 384 blocks
__global__ __launch_bounds__(256) void k_film1(
    const float* __restrict__ cond,
    const float* __restrict__ aw_film_w, const float* __restrict__ aw_zero_w,
    const float* __restrict__ fw_film_w, const float* __restrict__ fw_zero_w,
    float* __restrict__ FACC)
{
    int wid = blockIdx.x*4 + (threadIdx.x>>6);   // 0..1535
    int lane = threadIdx.x & 63;
    int kchunk = wid & 3;
    int colwave = wid >> 2;                      // 0..383
    int colinst0 = colwave << 6;
    int c = (colinst0 % 1536) + lane;
    int rest = colinst0 / 1536;                  // 0..15
    int b = rest & 1;
    int lt = rest >> 1;                          // 0..7
    int l = lt >> 1, t = lt & 1;
    const float* cr = cond + b*2048 + kchunk*512;
    const float* w; size_t stride;
    if (c < 1024){
        w = (t ? fw_film_w : aw_film_w) + (size_t)l*2048*1024 + (size_t)(kchunk*512)*1024 + c;
        stride = 1024;
    } else {
        w = (t ? fw_zero_w : aw_zero_w) + (size_t)l*2048*512 + (size_t)(kchunk*512)*512 + (c-1024);
        stride = 512;
    }
    float acc = 0.f;
    #pragma unroll 4
    for (int k=0;k<512;++k) acc += cr[k]*w[(size_t)k*stride];
    atomicAdd(&FACC[colinst0 + lane], acc);
}

__global__ void k_filmfin(const float* __restrict__ FACC,
    const float* __restrict__ aw_film_b, const float* __restrict__ aw_zero_b,
    const float* __restrict__ fw_film_b, const float* __restrict__ fw_zero_b,
    float* __restrict__ GAM, float* __restrict__ BET, float* __restrict__ GATE)
{
    int i = blockIdx.x*256+threadIdx.x;  // 24576
    if (i >= 24576) return;
    int c = i % 1536; int rest = i/1536; int b = rest&1; int lt = rest>>1; int l = lt>>1, t = lt&1;
    float v = FACC[i];
    if (c < 1024){
        v += (t ? fw_film_b : aw_film_b)[l*1024 + c];
        if (c < 512) GAM[(lt*2+b)*512 + c] = v;
        else         BET[(lt*2+b)*512 + (c-512)] = v;
    } else {
        v += (t ? fw_zero_b : aw_zero_b)[l*512 + (c-1024)];
        GATE[(lt*2+b)*512 + (c-1024)] = 1.f/(1.f+expf(-v));
    }
}

// fused layernorm -> FiLM/static modulation -> rmsnorm ; one wave per token
__global__ __launch_bounds__(256) void k_normmod(
    const float* __restrict__ X, const float* __restrict__ gamma, const float* __restrict__ beta,
    const float* __restrict__ lng, const float* __restrict__ ng,
    const unsigned char* __restrict__ modv, US* __restrict__ Y)
{
    int token = blockIdx.x*4 + (threadIdx.x>>6);
    int lane = threadIdx.x & 63;
    int b = token >> 11;
    const float* xr = X + ((size_t)token<<9);
    float v[8], s=0.f;
    #pragma unroll
    for (int j=0;j<8;++j){ v[j]=xr[(j<<6)+lane]; s+=v[j]; }
    s = wredsum(s);
    float mu = s*(1.f/512.f);
    float vs = 0.f;
    #pragma unroll
    for (int j=0;j<8;++j){ float d=v[j]-mu; vs+=d*d; }
    vs = wredsum(vs);
    float rsig = rsqrtf(vs*(1.f/512.f)+1e-5f);
    int md = modv[token];
    float xin[8], ss=0.f;
    #pragma unroll
    for (int j=0;j<8;++j){
        int d = (j<<6)+lane;
        float hn = (v[j]-mu)*rsig;
        float xi = md ? hn*(gamma[(b<<9)+d]+1.f)+beta[(b<<9)+d] : hn*(lng[d]+1.f);
        xin[j]=xi; ss+=xi*xi;
    }
    ss = wredsum(ss);
    float fac = 22.62741699796952f / fmaxf(sqrtf(ss), 1e-12f);
    #pragma unroll
    for (int j=0;j<8;++j){
        int d=(j<<6)+lane;
        Y[((size_t)token<<9)+d] = f2bf(xin[j]*fac*(ng[d]+1.f));
    }
}

__global__ __launch_bounds__(256) void k_final(const float* __restrict__ X, const float* __restrict__ g, float* __restrict__ out){
    int token = blockIdx.x*4 + (threadIdx.x>>6);
    int lane = threadIdx.x & 63;
    const float* xr = X + ((size_t)token<<9);
    float v[8], ss=0.f;
    #pragma unroll
    for (int j=0;j<8;++j){ v[j]=xr[(j<<6)+lane]; ss+=v[j]*v[j]; }
    ss=wredsum(ss);
    float fac = 22.62741699796952f / fmaxf(sqrtf(ss),1e-12f);
    #pragma unroll
    for (int j=0;j<8;++j){
        int d=(j<<6)+lane;
        out[((size_t)token<<9)+d] = v[j]*fac*(g[d]+1.f);
    }
}

__global__ void k_act(const US* __restrict__ u, US* __restrict__ act){
    int idx = blockIdx.x*256+threadIdx.x;
    if (idx >= 4096*1376) return;
    int t = idx / 1376, c = idx % 1376;
    float val = 0.f;
    if (c < 1365) {
        float a = bf2f(u[t*2752 + c]);
        float g = bf2f(u[t*2752 + 1365 + c]);
        val = 0.5f*g*(1.f+erff(g*0.70710678118f)) * a;
    }
    act[idx] = f2bf(val);
}

// ---------------- MFMA GEMM: C(MxN) = A(MxK) @ B(KxN), tiles 64x64x32, A/B bf16 ----------------
// EPI 0: store bf16 C. EPI 1: +bias(f32), store bf16 C.
// EPI 2: gate/scale select + residual add into fp32 X (N==512). EPI 3: +bias then as EPI 2.
template<int EPI>
__global__ __launch_bounds__(256) void k_gemm(
    const US* __restrict__ A, const US* __restrict__ Bm, US* __restrict__ C,
    const float* __restrict__ bias, float* __restrict__ X,
    const float* __restrict__ gate, const float* __restrict__ scale,
    const unsigned char* __restrict__ modv, int M, int N, int K)
{
    __shared__ US As[64*40];   // [row][k] row-major, pad 32->40
    __shared__ US Bs[64*40];   // transposed: [n][k]
    int tid = threadIdx.x;
    int wave = tid>>6, lane = tid&63, quad = lane>>4, l15 = lane&15;
    int m0 = blockIdx.y<<6, n0 = blockIdx.x<<6;
    f32x4 acc[4];
    #pragma unroll
    for (int nb=0;nb<4;++nb) acc[nb] = (f32x4){0.f,0.f,0.f,0.f};
    int arow = tid>>2, ac8 = (tid&3)<<3;
    int bn = tid&63, bk8 = (tid>>6)<<3;
    const US* Aptr = A + (size_t)(m0+arow)*K + ac8;
    const US* Bptr = Bm + n0 + bn;
    for (int k0=0;k0<K;k0+=32){
        __syncthreads();
        *(uint4*)&As[arow*40+ac8] = *(const uint4*)(Aptr + k0);
        {
            const US* bp = Bptr + (size_t)(k0+bk8)*N;
            unsigned int u0 = (unsigned int)bp[0]           | ((unsigned int)bp[(size_t)N]<<16);
            unsigned int u1 = (unsigned int)bp[2*(size_t)N] | ((unsigned int)bp[3*(size_t)N]<<16);
            unsigned int u2 = (unsigned int)bp[4*(size_t)N] | ((unsigned int)bp[5*(size_t)N]<<16);
            unsigned int u3 = (unsigned int)bp[6*(size_t)N] | ((unsigned int)bp[7*(size_t)N]<<16);
            uint4 wv; wv.x=u0; wv.y=u1; wv.z=u2; wv.w=u3;
            *(uint4*)&Bs[bn*40+bk8] = wv;
        }
        __syncthreads();
        short8 af = *(const short8*)&As[(wave*16+l15)*40 + (quad<<3)];
        #pragma unroll
        for (int nb=0;nb<4;++nb){
            short8 bf = *(const short8*)&Bs[((nb<<4)+l15)*40 + (quad<<3)];
            acc[nb] = __builtin_amdgcn_mfma_f32_16x16x32_bf16(af, bf, acc[nb], 0,0,0);
        }
    }
    #pragma unroll
    for (int nb=0;nb<4;++nb){
        int col = n0 + (nb<<4) + l15;
        #pragma unroll
        for (int r=0;r<4;++r){
            int row = m0 + wave*16 + (quad<<2) + r;
            float v = acc[nb][r];
            if (EPI==1 || EPI==3) v += bias[col];
            if (EPI<=1){
                C[(size_t)row*N + col] = f2bf(v);
            } else {
                float o = modv[row] ? v*gate[((row>>11)<<9) + col] : v*scale[col];
                X[((size_t)row<<9) + col] += o;
            }
        }
    }
}

// ---------------- MFMA flash attention, causal, softcap 50 ----------------
__global__ __launch_bounds__(256) void k_attn(const US* __restrict__ qkv, US* __restrict__ O)
{
    int blk = blockIdx.x;          // 512 blocks
    int rb = blk & 31, bh = blk >> 5;
    int b = bh >> 3, h = bh & 7;
    int tid = threadIdx.x, wave = tid>>6, lane = tid&63, quad = lane>>4, l15 = lane&15;
    __shared__ US Ks[64*72];       // [key][d]
    __shared__ US Vt[64*72];       // [d][key]
    __shared__ US Ps[4][16*72];    // per-wave P relayout [row][key]
    int qrow0 = (rb<<6) + (wave<<4);
    const US* qbase = qkv + (size_t)(b*2048 + qrow0 + l15)*1536 + h*64 + (quad<<3);
    short8 qf0 = *(const short8*)qbase;
    short8 qf1 = *(const short8*)(qbase + 32);
    f32x4 Oa[4];
    #pragma unroll
    for (int nb=0;nb<4;++nb) Oa[nb]=(f32x4){0.f,0.f,0.f,0.f};
    float m_r[4], l_r[4];
    #pragma unroll
    for (int r=0;r<4;++r){ m_r[r]=-1e30f; l_r[r]=0.f; }
    int nch = rb+1;
    for (int c=0;c<nch;++c){
        int j0 = c<<6;
        __syncthreads();
        #pragma unroll
        for (int it=0;it<2;++it){
            int g = tid + (it<<8);
            int key = g>>3, d8 = (g&7)<<3;
            *(uint4*)&Ks[key*72+d8] = *(const uint4*)(qkv + (size_t)(b*2048 + j0 + key)*1536 + 512 + h*64 + d8);
        }
        #pragma unroll
        for (int it=0;it<16;++it){
            int e = tid + (it<<8);
            int key = e>>6, d = e&63;
            Vt[d*72+key] = qkv[(size_t)(b*2048 + j0 + key)*1536 + 1024 + h*64 + d];
        }
        __syncthreads();
        f32x4 s[4];
        #pragma unroll
        for (int nb=0;nb<4;++nb){
            s[nb]=(f32x4){0.f,0.f,0.f,0.f};
            short8 kf0 = *(const short8*)&Ks[((nb<<4)+l15)*72 + (quad<<3)];
            short8 kf1 = *(const short8*)&Ks[((nb<<4)+l15)*72 + 32 + (quad<<3)];
            s[nb] = __builtin_amdgcn_mfma_f32_16x16x32_bf16(qf0, kf0, s[nb],0,0,0);
            s[nb] = __builtin_amdgcn_mfma_f32_16x16x32_bf16(qf1, kf1, s[nb],0,0,0);
        }
        float sims[4][4], mx[4];
        #pragma unroll
        for (int r=0;r<4;++r) mx[r]=-1e30f;
        #pragma unroll
        for (int nb=0;nb<4;++nb){
            int key = j0 + (nb<<4) + l15;
            #pragma unroll
            for (int r=0;r<4;++r){
                float sim = 50.f*tanhf(s[nb][r]*0.0025f);
                int rowg = qrow0 + (quad<<2) + r;
                if (key > rowg) sim = -1e30f;
                sims[nb][r]=sim;
                mx[r]=fmaxf(mx[r],sim);
            }
        }
        #pragma unroll
        for (int off=1; off<16; off<<=1){
            #pragma unroll
            for (int r=0;r<4;++r) mx[r]=fmaxf(mx[r], __shfl_xor(mx[r],off));
        }
        float alpha[4], sum[4];
        #pragma unroll
        for (int r=0;r<4;++r){
            float mn = fmaxf(m_r[r], mx[r]);
            alpha[r]=expf(m_r[r]-mn);
            m_r[r]=mn; sum[r]=0.f;
        }
        #pragma unroll
        for (int nb=0;nb<4;++nb){
            #pragma unroll
            for (int r=0;r<4;++r){
                float p = expf(sims[nb][r]-m_r[r]);
                sims[nb][r]=p; sum[r]+=p;
            }
        }
        #pragma unroll
        for (int off=1; off<16; off<<=1){
            #pragma unroll
            for (int r=0;r<4;++r) sum[r] += __shfl_xor(sum[r],off);
        }
        #pragma unroll
        for (int r=0;r<4;++r) l_r[r]=l_r[r]*alpha[r]+sum[r];
        #pragma unroll
        for (int nb=0;nb<4;++nb){
            #pragma unroll
            for (int r=0;r<4;++r) Oa[nb][r]*=alpha[r];
        }
        US* ps = &Ps[wave][0];
        #pragma unroll
        for (int nb=0;nb<4;++nb){
            #pragma unroll
            for (int r=0;r<4;++r)
                ps[((quad<<2)+r)*72 + (nb<<4)+l15] = f2bf(sims[nb][r]);
        }
        short8 pf0 = *(const short8*)&ps[l15*72 + (quad<<3)];
        short8 pf1 = *(const short8*)&ps[l15*72 + 32 + (quad<<3)];
        #pragma unroll
        for (int nb=0;nb<4;++nb){
            short8 vf0 = *(const short8*)&Vt[((nb<<4)+l15)*72 + (quad<<3)];
            short8 vf1 = *(const short8*)&Vt[((nb<<4)+l15)*72 + 32 + (quad<<3)];
            Oa[nb] = __builtin_amdgcn_mfma_f32_16x16x32_bf16(pf0, vf0, Oa[nb],0,0,0);
            Oa[nb] = __builtin_amdgcn_mfma_f32_16x16x32_bf16(pf1, vf1, Oa[nb],0,0,0);
        }
    }
    #pragma unroll
    for (int nb=0;nb<4;++nb){
        #pragma unroll
        for (int r=0;r<4;++r){
            int rowg = qrow0 + (quad<<2) + r;
            O[(size_t)(b*2048+rowg)*512 + h*64 + (nb<<4) + l15] = f2bf(Oa[nb][r]/fmaxf(l_r[r],1e-20f));
        }
    }
}

// ---------------- launcher ----------------
extern "C" void kernel_launch(void* const* d_in, const int* in_sizes, int n_in,
                              void* d_out, int out_size, void* d_ws, size_t ws_size,
                              hipStream_t stream)
{
    (void)in_sizes; (void)n_in; (void)out_size; (void)ws_size;
    const float* x        = (const float*)d_in[0];
    const float* times    = (const float*)d_in[1];
    const int*   mod_raw  = (const int*)d_in[3];   // attn_mask (d_in[2]) = causal tril, hardcoded
    const float* fourier  = (const float*)d_in[4];
    const float* time_w   = (const float*)d_in[5];
    const float* time_b   = (const float*)d_in[6];
    const float* aw_ln_g  = (const float*)d_in[7];
    const float* aw_scale = (const float*)d_in[8];
    const float* aw_film_w= (const float*)d_in[9];
    const float* aw_film_b= (const float*)d_in[10];
    const float* aw_zero_w= (const float*)d_in[11];
    const float* aw_zero_b= (const float*)d_in[12];
    const float* attn_norm_g=(const float*)d_in[13];
    const float* qkv_w    = (const float*)d_in[14];
    const float* out_w    = (const float*)d_in[15];
    const float* fw_ln_g  = (const float*)d_in[16];
    const float* fw_scale = (const float*)d_in[17];
    const float* fw_film_w= (const float*)d_in[18];
    const float* fw_film_b= (const float*)d_in[19];
    const float* fw_zero_w= (const float*)d_in[20];
    const float* fw_zero_b= (const float*)d_in[21];
    const float* ff_norm_g= (const float*)d_in[22];
    const float* ff_w1    = (const float*)d_in[23];
    const float* ff_b1    = (const float*)d_in[24];
    const float* ff_w2    = (const float*)d_in[25];
    const float* ff_b2    = (const float*)d_in[26];
    const float* final_g  = (const float*)d_in[27];

    char* ws = (char*)d_ws;
    size_t off = 0;
    auto alloc = [&](size_t bytes)->char*{ char* p = ws+off; off += (bytes + 255) & ~(size_t)255; return p; };
    float* Xf   = (float*)alloc(4096ull*512*4);
    US* Y       = (US*)alloc(4096ull*512*2);
    US* QKV     = (US*)alloc(4096ull*1536*2);
    US* Ob      = (US*)alloc(4096ull*512*2);
    US* U       = (US*)alloc(4096ull*2752*2);
    US* ACT     = (US*)alloc(4096ull*1376*2);
    US* QW      = (US*)alloc(4ull*512*1536*2);
    US* OW      = (US*)alloc(4ull*512*512*2);
    US* W1P     = (US*)alloc(4ull*512*2752*2);
    float* B1P  = (float*)alloc(4ull*2752*4);
    US* W2P     = (US*)alloc(4ull*1376*512*2);
    float* FEMB = (float*)alloc(2*513*4);
    float* CACC = (float*)alloc(4096*4);
    float* COND = (float*)alloc(2*2048*4);
    float* FACC = (float*)alloc(24576*4);
    float* GAM  = (float*)alloc(8192*4);   // [lt(4x2)][b][512]
    float* BET  = (float*)alloc(8192*4);
    float* GATE = (float*)alloc(8192*4);
    unsigned char* MOD = (unsigned char*)alloc(4096);
    int* FLAG   = (int*)alloc(256);

    k_copy<<<8192,256,0,stream>>>(x, Xf, 4096*512);
    k_detect<<<1,256,0,stream>>>(mod_raw, FLAG);
    k_mod<<<16,256,0,stream>>>(mod_raw, FLAG, MOD);
    k_f2b<<<(4*512*1536+255)/256,256,0,stream>>>(qkv_w, QW, 4*512*1536);
    k_f2b<<<(4*512*512+255)/256,256,0,stream>>>(out_w, OW, 4*512*512);
    k_padw1<<<(4*512*2752+255)/256,256,0,stream>>>(ff_w1, W1P);
    k_padb1<<<(4*2752+255)/256,256,0,stream>>>(ff_b1, B1P);
    k_padw2<<<(4*1376*512+255)/256,256,0,stream>>>(ff_w2, W2P);
    k_femb<<<5,256,0,stream>>>(times, fourier, FEMB);
    hipMemsetAsync(CACC, 0, 4096*4, stream);
    k_cond1<<<64,256,0,stream>>>(FEMB, time_w, CACC);
    k_condfin<<<16,256,0,stream>>>(CACC, time_b, COND);
    hipMemsetAsync(FACC, 0, 24576*4, stream);
    k_film1<<<384,256,0,stream>>>(COND, aw_film_w, aw_zero_w, fw_film_w, fw_zero_w, FACC);
    k_filmfin<<<96,256,0,stream>>>(FACC, aw_film_b, aw_zero_b, fw_film_b, fw_zero_b, GAM, BET, GATE);

    for (int l=0;l<4;++l){
        int lt0 = (l*2+0)*1024, lt1 = (l*2+1)*1024;
        // ---- attention block ----
        k_normmod<<<1024,256,0,stream>>>(Xf, GAM+lt0, BET+lt0, aw_ln_g + l*512, attn_norm_g + l*512, MOD, Y);
        k_gemm<0><<<dim3(1536/64,64),256,0,stream>>>(Y, QW + (size_t)l*512*1536, QKV,
                    nullptr, nullptr, nullptr, nullptr, nullptr, 4096,1536,512);
        k_attn<<<512,256,0,stream>>>(QKV, Ob);
        k_gemm<2><<<dim3(512/64,64),256,0,stream>>>(Ob, OW + (size_t)l*512*512, nullptr,
                    nullptr, Xf, GATE+lt0, aw_scale + l*512, MOD, 4096,512,512);
        // ---- feed-forward block ----
        k_normmod<<<1024,256,0,stream>>>(Xf, GAM+lt1, BET+lt1, fw_ln_g + l*512, ff_norm_g + l*512, MOD, Y);
        k_gemm<1><<<dim3(2752/64,64),256,0,stream>>>(Y, W1P + (size_t)l*512*2752, U,
                    B1P + l*2752, nullptr, nullptr, nullptr, nullptr, 4096,2752,512);
        k_act<<<(4096*1376+255)/256,256,0,stream>>>(U, ACT);
        k_gemm<3><<<dim3(512/64,64),256,0,stream>>>(ACT, W2P + (size_t)l*1376*512, nullptr,
                    ff_b2 + l*512, Xf, GATE+lt1, fw_scale + l*512, MOD, 4096,512,1376);
    }
    k_final<<<1024,256,0,stream>>>(Xf, final_g, (float*)d_out);
}

// Round 4
// 1020.777 us; speedup vs baseline: 2.3585x; 1.2843x over previous
//
#include <hip/hip_runtime.h>
#include <hip/hip_bf16.h>

typedef unsigned short US;
typedef short short8 __attribute__((ext_vector_type(8)));
typedef float f32x4 __attribute__((ext_vector_type(4)));

__device__ __forceinline__ float bf2f(US u){ union{unsigned int i; float f;}x; x.i=((unsigned int)u)<<16; return x.f; }
__device__ __forceinline__ US f2bf(float f){ union{float f; unsigned int i;}x; x.f=f; return (US)((x.i + 0x7fffu + ((x.i>>16)&1u))>>16); }

__device__ __forceinline__ float fastrcp(float x){
#if __has_builtin(__builtin_amdgcn_rcpf)
    return __builtin_amdgcn_rcpf(x);
#else
    return 1.f/x;
#endif
}

__device__ __forceinline__ float wredsum(float v){
    #pragma unroll
    for (int off=1; off<64; off<<=1) v += __shfl_xor(v, off);
    return v;
}

// ---------------- small prep kernels ----------------

__global__ void k_copy(const float* __restrict__ x, float* __restrict__ xf, int n){
    int i = blockIdx.x*256+threadIdx.x;
    if (i < n) xf[i] = x[i];
}

__global__ void k_f2b(const float* __restrict__ w, US* __restrict__ o, int n){
    int i = blockIdx.x*256+threadIdx.x;
    if (i < n) o[i] = f2bf(w[i]);
}

// detect whether is_any_modality is int32 (values 0/1) or byte-packed
__global__ void k_detect(const int* __restrict__ p, int* flag){
    __shared__ int f;
    if (threadIdx.x==0) f=0;
    __syncthreads();
    int bad=0;
    for (int i=threadIdx.x;i<1024;i+=256) if (((unsigned)p[i])>1u) bad=1;
    if (bad) atomicOr(&f,1);
    __syncthreads();
    if (threadIdx.x==0) *flag=f;
}
__global__ void k_mod(const int* __restrict__ p, const int* __restrict__ flag, unsigned char* __restrict__ mod){
    int t = blockIdx.x*256+threadIdx.x;
    if (t<4096){
        int v = (*flag) ? (int)(((const unsigned char*)p)[t]) : p[t];
        mod[t] = v?1:0;
    }
}

__global__ void k_padw1(const float* __restrict__ w, US* __restrict__ wp){ // (4,512,2730)->(4,512,2752) bf16
    int i = blockIdx.x*256+threadIdx.x;
    if (i >= 4*512*2752) return;
    int n = i % 2752; int lk = i / 2752;
    wp[i] = (n<2730) ? f2bf(w[lk*2730 + n]) : (US)0;
}
__global__ void k_padb1(const float* __restrict__ b, float* __restrict__ bp){
    int i = blockIdx.x*256+threadIdx.x;
    if (i >= 4*2752) return;
    int n = i % 2752; int l = i / 2752;
    bp[i] = (n<2730) ? b[l*2730+n] : 0.f;
}
__global__ void k_padw2(const float* __restrict__ w, US* __restrict__ wp){ // (4,1365,512)->(4,1376,512) bf16
    int i = blockIdx.x*256+threadIdx.x;
    if (i >= 4*1376*512) return;
    int n = i % 512; int r = i / 512; int k = r % 1376; int l = r / 1376;
    wp[i] = (k<1365) ? f2bf(w[(l*1365+k)*512 + n]) : (US)0;
}

__global__ void k_femb(const float* __restrict__ times, const float* __restrict__ fw, float* __restrict__ femb){
    int i = blockIdx.x*256 + threadIdx.x;
    if (i >= 2*513) return;
    int b = i / 513, k = i % 513;
    float t = times[b];
    float val;
    if (k == 0) val = t;
    else if (k <= 256) val = sinf(t * fw[k-1] * 6.2831853071795865f);
    else val = cosf(t * fw[k-257] * 6.2831853071795865f);
    femb[i] = val;
}

// cond matvec stage 1
__global__ __launch_bounds__(256) void k_cond1(const float* __restrict__ femb,
    const float* __restrict__ time_w, float* __restrict__ CACC)
{
    int wid = blockIdx.x*4 + (threadIdx.x>>6);   // 0..255
    int lane = threadIdx.x & 63;
    int kchunk = wid & 3;
    int colwave = wid >> 2;                      // 0..63
    int j = ((colwave & 31) << 6) + lane;        // 0..2047
    int b = colwave >> 5;
    int k0 = kchunk*129, k1 = k0+129; if (k1>513) k1=513;
    const float* fr = femb + b*513;
    float acc = 0.f;
    for (int k=k0;k<k1;++k) acc += fr[k]*time_w[(size_t)k*2048 + j];
    atomicAdd(&CACC[b*2048 + j], acc);
}
__global__ void k_condfin(const float* __restrict__ CACC, const float* __restrict__ time_b,
                          float* __restrict__ cond){
    int i = blockIdx.x*256+threadIdx.x;  // 4096
    if (i>=4096) return;
    float v = CACC[i] + time_b[i & 2047];
    cond[i] = v/(1.f+expf(-v));
}

// all-layer FiLM/gate matvec stage 1
__global__ __launch_bounds__(256) void k_film1(
    const float* __restrict__ cond,
    const float* __restrict__ aw_film_w, const float* __restrict__ aw_zero_w,
    const float* __restrict__ fw_film_w, const float* __restrict__ fw_zero_w,
    float* __restrict__ FACC)
{
    int wid = blockIdx.x*4 + (threadIdx.x>>6);   // 0..1535
    int lane = threadIdx.x & 63;
    int kchunk = wid & 3;
    int colwave = wid >> 2;                      // 0..383
    int colinst0 = colwave << 6;
    int c = (colinst0 % 1536) + lane;
    int rest = colinst0 / 1536;                  // 0..15
    int b = rest & 1;
    int lt = rest >> 1;                          // 0..7
    int l = lt >> 1, t = lt & 1;
    const float* cr = cond + b*2048 + kchunk*512;
    const float* w; size_t stride;
    if (c < 1024){
        w = (t ? fw_film_w : aw_film_w) + (size_t)l*2048*1024 + (size_t)(kchunk*512)*1024 + c;
        stride = 1024;
    } else {
        w = (t ? fw_zero_w : aw_zero_w) + (size_t)l*2048*512 + (size_t)(kchunk*512)*512 + (c-1024);
        stride = 512;
    }
    float acc = 0.f;
    #pragma unroll 4
    for (int k=0;k<512;++k) acc += cr[k]*w[(size_t)k*stride];
    atomicAdd(&FACC[colinst0 + lane], acc);
}

__global__ void k_filmfin(const float* __restrict__ FACC,
    const float* __restrict__ aw_film_b, const float* __restrict__ aw_zero_b,
    const float* __restrict__ fw_film_b, const float* __restrict__ fw_zero_b,
    float* __restrict__ GAM, float* __restrict__ BET, float* __restrict__ GATE)
{
    int i = blockIdx.x*256+threadIdx.x;  // 24576
    if (i >= 24576) return;
    int c = i % 1536; int rest = i/1536; int b = rest&1; int lt = rest>>1; int l = lt>>1, t = lt&1;
    float v = FACC[i];
    if (c < 1024){
        v += (t ? fw_film_b : aw_film_b)[l*1024 + c];
        if (c < 512) GAM[(lt*2+b)*512 + c] = v;
        else         BET[(lt*2+b)*512 + (c-512)] = v;
    } else {
        v += (t ? fw_zero_b : aw_zero_b)[l*512 + (c-1024)];
        GATE[(lt*2+b)*512 + (c-1024)] = 1.f/(1.f+expf(-v));
    }
}

// fused layernorm -> FiLM/static modulation -> rmsnorm ; one wave per token
__global__ __launch_bounds__(256) void k_normmod(
    const float* __restrict__ X, const float* __restrict__ gamma, const float* __restrict__ beta,
    const float* __restrict__ lng, const float* __restrict__ ng,
    const unsigned char* __restrict__ modv, US* __restrict__ Y)
{
    int token = blockIdx.x*4 + (threadIdx.x>>6);
    int lane = threadIdx.x & 63;
    int b = token >> 11;
    const float* xr = X + ((size_t)token<<9);
    float v[8], s=0.f;
    #pragma unroll
    for (int j=0;j<8;++j){ v[j]=xr[(j<<6)+lane]; s+=v[j]; }
    s = wredsum(s);
    float mu = s*(1.f/512.f);
    float vs = 0.f;
    #pragma unroll
    for (int j=0;j<8;++j){ float d=v[j]-mu; vs+=d*d; }
    vs = wredsum(vs);
    float rsig = rsqrtf(vs*(1.f/512.f)+1e-5f);
    int md = modv[token];
    float xin[8], ss=0.f;
    #pragma unroll
    for (int j=0;j<8;++j){
        int d = (j<<6)+lane;
        float hn = (v[j]-mu)*rsig;
        float xi = md ? hn*(gamma[(b<<9)+d]+1.f)+beta[(b<<9)+d] : hn*(lng[d]+1.f);
        xin[j]=xi; ss+=xi*xi;
    }
    ss = wredsum(ss);
    float fac = 22.62741699796952f / fmaxf(sqrtf(ss), 1e-12f);
    #pragma unroll
    for (int j=0;j<8;++j){
        int d=(j<<6)+lane;
        Y[((size_t)token<<9)+d] = f2bf(xin[j]*fac*(ng[d]+1.f));
    }
}

__global__ __launch_bounds__(256) void k_final(const float* __restrict__ X, const float* __restrict__ g, float* __restrict__ out){
    int token = blockIdx.x*4 + (threadIdx.x>>6);
    int lane = threadIdx.x & 63;
    const float* xr = X + ((size_t)token<<9);
    float v[8], ss=0.f;
    #pragma unroll
    for (int j=0;j<8;++j){ v[j]=xr[(j<<6)+lane]; ss+=v[j]*v[j]; }
    ss=wredsum(ss);
    float fac = 22.62741699796952f / fmaxf(sqrtf(ss),1e-12f);
    #pragma unroll
    for (int j=0;j<8;++j){
        int d=(j<<6)+lane;
        out[((size_t)token<<9)+d] = v[j]*fac*(g[d]+1.f);
    }
}

__global__ void k_act(const US* __restrict__ u, US* __restrict__ act){
    int idx = blockIdx.x*256+threadIdx.x;
    if (idx >= 4096*1376) return;
    int t = idx / 1376, c = idx % 1376;
    float val = 0.f;
    if (c < 1365) {
        float a = bf2f(u[t*2752 + c]);
        float g = bf2f(u[t*2752 + 1365 + c]);
        val = 0.5f*g*(1.f+erff(g*0.70710678118f)) * a;
    }
    act[idx] = f2bf(val);
}

// ---------------- MFMA GEMM: C(MxN) = A(MxK) @ B(KxN), tiles 64x64x32, A/B bf16 ----------------
template<int EPI>
__global__ __launch_bounds__(256) void k_gemm(
    const US* __restrict__ A, const US* __restrict__ Bm, US* __restrict__ C,
    const float* __restrict__ bias, float* __restrict__ X,
    const float* __restrict__ gate, const float* __restrict__ scale,
    const unsigned char* __restrict__ modv, int M, int N, int K)
{
    __shared__ US As[64*40];   // [row][k] row-major, pad 32->40
    __shared__ US Bs[64*40];   // transposed: [n][k]
    int tid = threadIdx.x;
    int wave = tid>>6, lane = tid&63, quad = lane>>4, l15 = lane&15;
    int m0 = blockIdx.y<<6, n0 = blockIdx.x<<6;
    f32x4 acc[4];
    #pragma unroll
    for (int nb=0;nb<4;++nb) acc[nb] = (f32x4){0.f,0.f,0.f,0.f};
    int arow = tid>>2, ac8 = (tid&3)<<3;
    int bn = tid&63, bk8 = (tid>>6)<<3;
    const US* Aptr = A + (size_t)(m0+arow)*K + ac8;
    const US* Bptr = Bm + n0 + bn;
    for (int k0=0;k0<K;k0+=32){
        __syncthreads();
        *(uint4*)&As[arow*40+ac8] = *(const uint4*)(Aptr + k0);
        {
            const US* bp = Bptr + (size_t)(k0+bk8)*N;
            unsigned int u0 = (unsigned int)bp[0]           | ((unsigned int)bp[(size_t)N]<<16);
            unsigned int u1 = (unsigned int)bp[2*(size_t)N] | ((unsigned int)bp[3*(size_t)N]<<16);
            unsigned int u2 = (unsigned int)bp[4*(size_t)N] | ((unsigned int)bp[5*(size_t)N]<<16);
            unsigned int u3 = (unsigned int)bp[6*(size_t)N] | ((unsigned int)bp[7*(size_t)N]<<16);
            uint4 wv; wv.x=u0; wv.y=u1; wv.z=u2; wv.w=u3;
            *(uint4*)&Bs[bn*40+bk8] = wv;
        }
        __syncthreads();
        short8 af = *(const short8*)&As[(wave*16+l15)*40 + (quad<<3)];
        #pragma unroll
        for (int nb=0;nb<4;++nb){
            short8 bf = *(const short8*)&Bs[((nb<<4)+l15)*40 + (quad<<3)];
            acc[nb] = __builtin_amdgcn_mfma_f32_16x16x32_bf16(af, bf, acc[nb], 0,0,0);
        }
    }
    #pragma unroll
    for (int nb=0;nb<4;++nb){
        int col = n0 + (nb<<4) + l15;
        #pragma unroll
        for (int r=0;r<4;++r){
            int row = m0 + wave*16 + (quad<<2) + r;
            float v = acc[nb][r];
            if (EPI==1 || EPI==3) v += bias[col];
            if (EPI<=1){
                C[(size_t)row*N + col] = f2bf(v);
            } else {
                float o = modv[row] ? v*gate[((row>>11)<<9) + col] : v*scale[col];
                X[((size_t)row<<9) + col] += o;
            }
        }
    }
}

// ---------------- V transpose: qkv V-part -> VT[bh][d(64)][key(2048)] ----------------
__global__ __launch_bounds__(256) void k_vtrans(const US* __restrict__ qkv, US* __restrict__ VT){
    __shared__ US Ts[64*72];
    int bh = blockIdx.y;               // 0..15
    int kt = blockIdx.x;               // 0..31 (64-key tiles)
    int b = bh>>3, h = bh&7;
    int tid = threadIdx.x;
    #pragma unroll
    for (int it=0; it<2; ++it){
        int idx = tid + (it<<8);
        int key = idx>>3, d8 = (idx&7)<<3;
        *(uint4*)&Ts[key*72 + d8] =
            *(const uint4*)(qkv + (size_t)(b*2048 + kt*64 + key)*1536 + 1024 + h*64 + d8);
    }
    __syncthreads();
    #pragma unroll
    for (int it=0; it<2; ++it){
        int oidx = tid + (it<<8);
        int d = oidx>>3, kb = (oidx&7)<<3;
        US tmp[8];
        #pragma unroll
        for (int j=0;j<8;++j) tmp[j] = Ts[(kb+j)*72 + d];
        *(uint4*)(VT + (size_t)bh*131072 + (size_t)d*2048 + kt*64 + kb) = *(uint4*)tmp;
    }
}

// ---------------- MFMA flash attention, causal, softcap 50 ----------------
// 256 blocks: bh (16) x pair (16); each block processes q-tiles rb=p and rb=31-p (33 chunks total).
__global__ __launch_bounds__(256) void k_attn(const US* __restrict__ qkv, const US* __restrict__ VT,
                                              US* __restrict__ O)
{
    int blk = blockIdx.x;              // 256
    int bh = blk >> 4, p = blk & 15;
    int b = bh >> 3, h = bh & 7;
    int tid = threadIdx.x, wave = tid>>6, lane = tid&63, quad = lane>>4, l15 = lane&15;
    __shared__ US Ks[64*72];           // [key][d]
    __shared__ US Vt[64*72];           // [d][key]
    __shared__ US Ps[4*16*72];         // per-wave P relayout [row][key], 16B-group XOR swizzle by row&3
    US* ps = Ps + wave*16*72;

    // staging index math (per thread, 2 iterations each for K and V)
    int skey0 = tid>>3,  soff0 = (tid&7)<<3;    // K: [key][d8]
    const US* Kg = qkv + (size_t)(b*2048)*1536 + 512 + h*64;
    const US* Vg = VT + (size_t)bh*131072;       // [d][2048]

    int rbs[2] = {p, 31-p};
    #pragma unroll
    for (int ti=0; ti<2; ++ti){
        int rb = rbs[ti];
        int qrow0 = (rb<<6) + (wave<<4);
        const US* qbase = qkv + (size_t)(b*2048 + qrow0 + l15)*1536 + h*64 + (quad<<3);
        short8 qf0 = *(const short8*)qbase;
        short8 qf1 = *(const short8*)(qbase + 32);
        f32x4 Oa[4];
        #pragma unroll
        for (int nb=0;nb<4;++nb) Oa[nb]=(f32x4){0.f,0.f,0.f,0.f};
        float lsum[4] = {0.f,0.f,0.f,0.f};

        // prefetch chunk 0
        uint4 ka0 = *(const uint4*)(Kg + (size_t)(skey0)*1536 + soff0);
        uint4 ka1 = *(const uint4*)(Kg + (size_t)(skey0+32)*1536 + soff0);
        uint4 va0 = *(const uint4*)(Vg + (size_t)(skey0)*2048 + soff0);
        uint4 va1 = *(const uint4*)(Vg + (size_t)(skey0+32)*2048 + soff0);

        for (int c=0; c<=rb; ++c){
            int j0 = c<<6;
            __syncthreads();
            *(uint4*)&Ks[skey0*72 + soff0]      = ka0;
            *(uint4*)&Ks[(skey0+32)*72 + soff0] = ka1;
            *(uint4*)&Vt[skey0*72 + soff0]      = va0;
            *(uint4*)&Vt[(skey0+32)*72 + soff0] = va1;
            __syncthreads();
            if (c < rb){
                int j1 = j0 + 64;
                ka0 = *(const uint4*)(Kg + (size_t)(j1+skey0)*1536 + soff0);
                ka1 = *(const uint4*)(Kg + (size_t)(j1+skey0+32)*1536 + soff0);
                va0 = *(const uint4*)(Vg + (size_t)(skey0)*2048 + j1 + soff0);
                va1 = *(const uint4*)(Vg + (size_t)(skey0+32)*2048 + j1 + soff0);
            }
            // QK^T
            f32x4 s[4];
            #pragma unroll
            for (int nb=0;nb<4;++nb){
                s[nb]=(f32x4){0.f,0.f,0.f,0.f};
                short8 kf0 = *(const short8*)&Ks[((nb<<4)+l15)*72 + (quad<<3)];
                short8 kf1 = *(const short8*)&Ks[((nb<<4)+l15)*72 + 32 + (quad<<3)];
                s[nb] = __builtin_amdgcn_mfma_f32_16x16x32_bf16(qf0, kf0, s[nb],0,0,0);
                s[nb] = __builtin_amdgcn_mfma_f32_16x16x32_bf16(qf1, kf1, s[nb],0,0,0);
            }
            // softcap + exp (fixed max=0: softcap bounds |sim|<=50, e^50 fp32-safe)
            int diag = (c==rb);
            #pragma unroll
            for (int nb=0;nb<4;++nb){
                int grp = (nb<<1) + (l15>>3);
                #pragma unroll
                for (int r=0;r<4;++r){
                    // sim = 50*tanh(s*0.0025); tanh via 1-2/(e^{2x}+1), NaN-free at +-inf
                    float e2 = __expf(s[nb][r]*0.005f);
                    float t = 1.f - 2.f*fastrcp(e2+1.f);
                    float pv = __expf(50.f*t);
                    if (diag){
                        int key = j0 + (nb<<4) + l15;
                        int rowg = qrow0 + (quad<<2) + r;
                        if (key > rowg) pv = 0.f;
                    }
                    lsum[r] += pv;
                    ps[((quad<<2)+r)*72 + ((grp^r)<<3) + (l15&7)] = f2bf(pv);
                }
            }
            // read P in A-operand layout (swizzle-aware), PV
            int gs0 = quad ^ (l15&3);
            int gs1 = (4+quad) ^ (l15&3);
            short8 pf0 = *(const short8*)&ps[l15*72 + (gs0<<3)];
            short8 pf1 = *(const short8*)&ps[l15*72 + (gs1<<3)];
            #pragma unroll
            for (int nb=0;nb<4;++nb){
                short8 vf0 = *(const short8*)&Vt[((nb<<4)+l15)*72 + (quad<<3)];
                short8 vf1 = *(const short8*)&Vt[((nb<<4)+l15)*72 + 32 + (quad<<3)];
                Oa[nb] = __builtin_amdgcn_mfma_f32_16x16x32_bf16(pf0, vf0, Oa[nb],0,0,0);
                Oa[nb] = __builtin_amdgcn_mfma_f32_16x16x32_bf16(pf1, vf1, Oa[nb],0,0,0);
            }
        }
        // deferred l reduction across the 16 lanes of each row group
        float inv[4];
        #pragma unroll
        for (int r=0;r<4;++r){
            float v = lsum[r];
            v += __shfl_xor(v,1); v += __shfl_xor(v,2);
            v += __shfl_xor(v,4); v += __shfl_xor(v,8);
            inv[r] = 1.f / fmaxf(v, 1e-30f);
        }
        #pragma unroll
        for (int nb=0;nb<4;++nb){
            #pragma unroll
            for (int r=0;r<4;++r){
                int rowg = qrow0 + (quad<<2) + r;
                O[(size_t)(b*2048+rowg)*512 + h*64 + (nb<<4) + l15] = f2bf(Oa[nb][r]*inv[r]);
            }
        }
    }
}

// ---------------- launcher ----------------
extern "C" void kernel_launch(void* const* d_in, const int* in_sizes, int n_in,
                              void* d_out, int out_size, void* d_ws, size_t ws_size,
                              hipStream_t stream)
{
    (void)in_sizes; (void)n_in; (void)out_size; (void)ws_size;
    const float* x        = (const float*)d_in[0];
    const float* times    = (const float*)d_in[1];
    const int*   mod_raw  = (const int*)d_in[3];   // attn_mask (d_in[2]) = causal tril, hardcoded
    const float* fourier  = (const float*)d_in[4];
    const float* time_w   = (const float*)d_in[5];
    const float* time_b   = (const float*)d_in[6];
    const float* aw_ln_g  = (const float*)d_in[7];
    const float* aw_scale = (const float*)d_in[8];
    const float* aw_film_w= (const float*)d_in[9];
    const float* aw_film_b= (const float*)d_in[10];
    const float* aw_zero_w= (const float*)d_in[11];
    const float* aw_zero_b= (const float*)d_in[12];
    const float* attn_norm_g=(const float*)d_in[13];
    const float* qkv_w    = (const float*)d_in[14];
    const float* out_w    = (const float*)d_in[15];
    const float* fw_ln_g  = (const float*)d_in[16];
    const float* fw_scale = (const float*)d_in[17];
    const float* fw_film_w= (const float*)d_in[18];
    const float* fw_film_b= (const float*)d_in[19];
    const float* fw_zero_w= (const float*)d_in[20];
    const float* fw_zero_b= (const float*)d_in[21];
    const float* ff_norm_g= (const float*)d_in[22];
    const float* ff_w1    = (const float*)d_in[23];
    const float* ff_b1    = (const float*)d_in[24];
    const float* ff_w2    = (const float*)d_in[25];
    const float* ff_b2    = (const float*)d_in[26];
    const float* final_g  = (const float*)d_in[27];

    char* ws = (char*)d_ws;
    size_t off = 0;
    auto alloc = [&](size_t bytes)->char*{ char* p = ws+off; off += (bytes + 255) & ~(size_t)255; return p; };
    float* Xf   = (float*)alloc(4096ull*512*4);
    US* Y       = (US*)alloc(4096ull*512*2);
    US* QKV     = (US*)alloc(4096ull*1536*2);
    US* VT      = (US*)alloc(16ull*64*2048*2);
    US* Ob      = (US*)alloc(4096ull*512*2);
    US* U       = (US*)alloc(4096ull*2752*2);
    US* ACT     = (US*)alloc(4096ull*1376*2);
    US* QW      = (US*)alloc(4ull*512*1536*2);
    US* OW      = (US*)alloc(4ull*512*512*2);
    US* W1P     = (US*)alloc(4ull*512*2752*2);
    float* B1P  = (float*)alloc(4ull*2752*4);
    US* W2P     = (US*)alloc(4ull*1376*512*2);
    float* FEMB = (float*)alloc(2*513*4);
    float* CACC = (float*)alloc(4096*4);
    float* COND = (float*)alloc(2*2048*4);
    float* FACC = (float*)alloc(24576*4);
    float* GAM  = (float*)alloc(8192*4);   // [lt(4x2)][b][512]
    float* BET  = (float*)alloc(8192*4);
    float* GATE = (float*)alloc(8192*4);
    unsigned char* MOD = (unsigned char*)alloc(4096);
    int* FLAG   = (int*)alloc(256);

    k_copy<<<8192,256,0,stream>>>(x, Xf, 4096*512);
    k_detect<<<1,256,0,stream>>>(mod_raw, FLAG);
    k_mod<<<16,256,0,stream>>>(mod_raw, FLAG, MOD);
    k_f2b<<<(4*512*1536+255)/256,256,0,stream>>>(qkv_w, QW, 4*512*1536);
    k_f2b<<<(4*512*512+255)/256,256,0,stream>>>(out_w, OW, 4*512*512);
    k_padw1<<<(4*512*2752+255)/256,256,0,stream>>>(ff_w1, W1P);
    k_padb1<<<(4*2752+255)/256,256,0,stream>>>(ff_b1, B1P);
    k_padw2<<<(4*1376*512+255)/256,256,0,stream>>>(ff_w2, W2P);
    k_femb<<<5,256,0,stream>>>(times, fourier, FEMB);
    hipMemsetAsync(CACC, 0, 4096*4, stream);
    k_cond1<<<64,256,0,stream>>>(FEMB, time_w, CACC);
    k_condfin<<<16,256,0,stream>>>(CACC, time_b, COND);
    hipMemsetAsync(FACC, 0, 24576*4, stream);
    k_film1<<<384,256,0,stream>>>(COND, aw_film_w, aw_zero_w, fw_film_w, fw_zero_w, FACC);
    k_filmfin<<<96,256,0,stream>>>(FACC, aw_film_b, aw_zero_b, fw_film_b, fw_zero_b, GAM, BET, GATE);

    for (int l=0;l<4;++l){
        int lt0 = (l*2+0)*1024, lt1 = (l*2+1)*1024;
        // ---- attention block ----
        k_normmod<<<1024,256,0,stream>>>(Xf, GAM+lt0, BET+lt0, aw_ln_g + l*512, attn_norm_g + l*512, MOD, Y);
        k_gemm<0><<<dim3(1536/64,64),256,0,stream>>>(Y, QW + (size_t)l*512*1536, QKV,
                    nullptr, nullptr, nullptr, nullptr, nullptr, 4096,1536,512);
        k_vtrans<<<dim3(32,16),256,0,stream>>>(QKV, VT);
        k_attn<<<256,256,0,stream>>>(QKV, VT, Ob);
        k_gemm<2><<<dim3(512/64,64),256,0,stream>>>(Ob, OW + (size_t)l*512*512, nullptr,
                    nullptr, Xf, GATE+lt0, aw_scale + l*512, MOD, 4096,512,512);
        // ---- feed-forward block ----
        k_normmod<<<1024,256,0,stream>>>(Xf, GAM+lt1, BET+lt1, fw_ln_g + l*512, ff_norm_g + l*512, MOD, Y);
        k_gemm<1><<<dim3(2752/64,64),256,0,stream>>>(Y, W1P + (size_t)l*512*2752, U,
                    B1P + l*2752, nullptr, nullptr, nullptr, nullptr, 4096,2752,512);
        k_act<<<(4096*1376+255)/256,256,0,stream>>>(U, ACT);
        k_gemm<3><<<dim3(512/64,64),256,0,stream>>>(ACT, W2P + (size_t)l*1376*512, nullptr,
                    ff_b2 + l*512, Xf, GATE+lt1, fw_scale + l*512, MOD, 4096,512,1376);
    }
    k_final<<<1024,256,0,stream>>>(Xf, final_g, (float*)d_out);
}

// Round 5
// 965.845 us; speedup vs baseline: 2.4926x; 1.0569x over previous
//
#include <hip/hip_runtime.h>
#include <hip/hip_bf16.h>

typedef unsigned short US;
typedef short short8 __attribute__((ext_vector_type(8)));
typedef float f32x4 __attribute__((ext_vector_type(4)));

__device__ __forceinline__ float bf2f(US u){ union{unsigned int i; float f;}x; x.i=((unsigned int)u)<<16; return x.f; }
__device__ __forceinline__ US f2bf(float f){ union{float f; unsigned int i;}x; x.f=f; return (US)((x.i + 0x7fffu + ((x.i>>16)&1u))>>16); }

__device__ __forceinline__ float fastrcp(float x){
#if __has_builtin(__builtin_amdgcn_rcpf)
    return __builtin_amdgcn_rcpf(x);
#else
    return 1.f/x;
#endif
}

__device__ __forceinline__ void gload_lds16(const US* g, US* l){
    __builtin_amdgcn_global_load_lds(
        (const __attribute__((address_space(1))) unsigned int*)g,
        (__attribute__((address_space(3))) unsigned int*)l, 16, 0, 0);
}

__device__ __forceinline__ float wredsum(float v){
    #pragma unroll
    for (int off=1; off<64; off<<=1) v += __shfl_xor(v, off);
    return v;
}

// ---------------- small prep kernels ----------------

__global__ void k_copy(const float* __restrict__ x, float* __restrict__ xf, int n){
    int i = blockIdx.x*256+threadIdx.x;
    if (i < n) xf[i] = x[i];
}

// detect whether is_any_modality is int32 (values 0/1) or byte-packed
__global__ void k_detect(const int* __restrict__ p, int* flag){
    __shared__ int f;
    if (threadIdx.x==0) f=0;
    __syncthreads();
    int bad=0;
    for (int i=threadIdx.x;i<1024;i+=256) if (((unsigned)p[i])>1u) bad=1;
    if (bad) atomicOr(&f,1);
    __syncthreads();
    if (threadIdx.x==0) *flag=f;
}
__global__ void k_mod(const int* __restrict__ p, const int* __restrict__ flag, unsigned char* __restrict__ mod){
    int t = blockIdx.x*256+threadIdx.x;
    if (t<4096){
        int v = (*flag) ? (int)(((const unsigned char*)p)[t]) : p[t];
        mod[t] = v?1:0;
    }
}

// transpose + bf16 + pad: src fp32 [L][Ks][N] -> dst bf16 [L][Npad][Kd] (dst[n][k]=src[k][n], zero-pad)
__global__ __launch_bounds__(256) void k_wt(const float* __restrict__ src, US* __restrict__ dst,
                                            int Ks, int N, int Kd, int Npad){
    int l = blockIdx.z;
    src += (size_t)l*Ks*N;
    dst += (size_t)l*Npad*Kd;
    __shared__ US T[64*65];
    int k0 = blockIdx.x<<6, n0 = blockIdx.y<<6;
    int tid = threadIdx.x;
    #pragma unroll
    for (int it=0; it<16; ++it){
        int idx = (it<<8) + tid;
        int r = idx>>6, c = idx&63;     // r: k, c: n
        int kk = k0+r, nn = n0+c;
        float v = (kk<Ks && nn<N) ? src[(size_t)kk*N+nn] : 0.f;
        T[c*65+r] = f2bf(v);
    }
    __syncthreads();
    int g = tid&7, rr = tid>>3;   // rr 0..31
    if (k0 + (g<<3) < Kd){
        #pragma unroll
        for (int half=0; half<2; ++half){
            int nn = rr + (half<<5);
            US tmp[8];
            #pragma unroll
            for (int j=0;j<8;++j) tmp[j] = T[nn*65 + (g<<3)+j];
            *(uint4*)(dst + (size_t)(n0+nn)*Kd + k0 + (g<<3)) = *(uint4*)tmp;
        }
    }
}

__global__ void k_padb1(const float* __restrict__ b, float* __restrict__ bp){ // (4,2730)->(4,2816)
    int i = blockIdx.x*256+threadIdx.x;
    if (i >= 4*2816) return;
    int n = i % 2816; int l = i / 2816;
    bp[i] = (n<2730) ? b[l*2730+n] : 0.f;
}

__global__ void k_femb(const float* __restrict__ times, const float* __restrict__ fw, float* __restrict__ femb){
    int i = blockIdx.x*256 + threadIdx.x;
    if (i >= 2*513) return;
    int b = i / 513, k = i % 513;
    float t = times[b];
    float val;
    if (k == 0) val = t;
    else if (k <= 256) val = sinf(t * fw[k-1] * 6.2831853071795865f);
    else val = cosf(t * fw[k-257] * 6.2831853071795865f);
    femb[i] = val;
}

// cond matvec stage 1
__global__ __launch_bounds__(256) void k_cond1(const float* __restrict__ femb,
    const float* __restrict__ time_w, float* __restrict__ CACC)
{
    int wid = blockIdx.x*4 + (threadIdx.x>>6);   // 0..255
    int lane = threadIdx.x & 63;
    int kchunk = wid & 3;
    int colwave = wid >> 2;                      // 0..63
    int j = ((colwave & 31) << 6) + lane;        // 0..2047
    int b = colwave >> 5;
    int k0 = kchunk*129, k1 = k0+129; if (k1>513) k1=513;
    const float* fr = femb + b*513;
    float acc = 0.f;
    for (int k=k0;k<k1;++k) acc += fr[k]*time_w[(size_t)k*2048 + j];
    atomicAdd(&CACC[b*2048 + j], acc);
}
__global__ void k_condfin(const float* __restrict__ CACC, const float* __restrict__ time_b,
                          float* __restrict__ cond){
    int i = blockIdx.x*256+threadIdx.x;  // 4096
    if (i>=4096) return;
    float v = CACC[i] + time_b[i & 2047];
    cond[i] = v/(1.f+expf(-v));
}

// FiLM matrices (8 of [2048][1024]): 256 blocks = 8 lt x 32 kchunks(64)
__global__ __launch_bounds__(256) void k_film2f(const float* __restrict__ cond,
    const float* __restrict__ aw_film_w, const float* __restrict__ fw_film_w,
    float* __restrict__ FACC)
{
    __shared__ float cs[2][64];
    int blk = blockIdx.x;
    int lt = blk>>5, kc = blk&31;
    int l = lt>>1, t = lt&1;
    const float* W = (t? fw_film_w : aw_film_w) + (size_t)l*2048*1024 + ((size_t)(kc<<6))*1024;
    int tid = threadIdx.x;
    if (tid < 128) cs[tid>>6][tid&63] = cond[(tid>>6)*2048 + (kc<<6) + (tid&63)];
    __syncthreads();
    int c4 = tid<<2;
    float a0=0,a1=0,a2=0,a3=0,b0=0,b1=0,b2=0,b3=0;
    #pragma unroll 4
    for (int k=0;k<64;++k){
        float4 w = *(const float4*)&W[(size_t)k*1024 + c4];
        float c0 = cs[0][k], c1 = cs[1][k];
        a0 += c0*w.x; a1 += c0*w.y; a2 += c0*w.z; a3 += c0*w.w;
        b0 += c1*w.x; b1 += c1*w.y; b2 += c1*w.z; b3 += c1*w.w;
    }
    float* F0 = &FACC[(lt*2+0)*1536 + c4];
    float* F1 = &FACC[(lt*2+1)*1536 + c4];
    atomicAdd(F0+0,a0); atomicAdd(F0+1,a1); atomicAdd(F0+2,a2); atomicAdd(F0+3,a3);
    atomicAdd(F1+0,b0); atomicAdd(F1+1,b1); atomicAdd(F1+2,b2); atomicAdd(F1+3,b3);
}

// zero matrices (8 of [2048][512]): 256 blocks = 8 lt x 32 kchunks(64); k split 2x32 across thread halves
__global__ __launch_bounds__(256) void k_film2z(const float* __restrict__ cond,
    const float* __restrict__ aw_zero_w, const float* __restrict__ fw_zero_w,
    float* __restrict__ FACC)
{
    __shared__ float cs[2][64];
    int blk = blockIdx.x;
    int lt = blk>>5, kc = blk&31;
    int l = lt>>1, t = lt&1;
    int tid = threadIdx.x;
    if (tid < 128) cs[tid>>6][tid&63] = cond[(tid>>6)*2048 + (kc<<6) + (tid&63)];
    __syncthreads();
    int kh = tid>>7;                 // 0/1
    int c4 = (tid&127)<<2;           // 512 cols
    const float* W = (t? fw_zero_w : aw_zero_w) + (size_t)l*2048*512 + ((size_t)((kc<<6)+(kh<<5)))*512;
    float a0=0,a1=0,a2=0,a3=0,b0=0,b1=0,b2=0,b3=0;
    #pragma unroll 4
    for (int k=0;k<32;++k){
        float4 w = *(const float4*)&W[(size_t)k*512 + c4];
        float c0 = cs[0][(kh<<5)+k], c1 = cs[1][(kh<<5)+k];
        a0 += c0*w.x; a1 += c0*w.y; a2 += c0*w.z; a3 += c0*w.w;
        b0 += c1*w.x; b1 += c1*w.y; b2 += c1*w.z; b3 += c1*w.w;
    }
    float* F0 = &FACC[(lt*2+0)*1536 + 1024 + c4];
    float* F1 = &FACC[(lt*2+1)*1536 + 1024 + c4];
    atomicAdd(F0+0,a0); atomicAdd(F0+1,a1); atomicAdd(F0+2,a2); atomicAdd(F0+3,a3);
    atomicAdd(F1+0,b0); atomicAdd(F1+1,b1); atomicAdd(F1+2,b2); atomicAdd(F1+3,b3);
}

__global__ void k_filmfin(const float* __restrict__ FACC,
    const float* __restrict__ aw_film_b, const float* __restrict__ aw_zero_b,
    const float* __restrict__ fw_film_b, const float* __restrict__ fw_zero_b,
    float* __restrict__ GAM, float* __restrict__ BET, float* __restrict__ GATE)
{
    int i = blockIdx.x*256+threadIdx.x;  // 24576
    if (i >= 24576) return;
    int c = i % 1536; int rest = i/1536; int b = rest&1; int lt = rest>>1; int l = lt>>1, t = lt&1;
    float v = FACC[i];
    if (c < 1024){
        v += (t ? fw_film_b : aw_film_b)[l*1024 + c];
        if (c < 512) GAM[(lt*2+b)*512 + c] = v;
        else         BET[(lt*2+b)*512 + (c-512)] = v;
    } else {
        v += (t ? fw_zero_b : aw_zero_b)[l*512 + (c-1024)];
        GATE[(lt*2+b)*512 + (c-1024)] = 1.f/(1.f+expf(-v));
    }
}

// fused layernorm -> FiLM/static modulation -> rmsnorm ; one wave per token
__global__ __launch_bounds__(256) void k_normmod(
    const float* __restrict__ X, const float* __restrict__ gamma, const float* __restrict__ beta,
    const float* __restrict__ lng, const float* __restrict__ ng,
    const unsigned char* __restrict__ modv, US* __restrict__ Y)
{
    int token = blockIdx.x*4 + (threadIdx.x>>6);
    int lane = threadIdx.x & 63;
    int b = token >> 11;
    const float* xr = X + ((size_t)token<<9);
    float v[8], s=0.f;
    #pragma unroll
    for (int j=0;j<8;++j){ v[j]=xr[(j<<6)+lane]; s+=v[j]; }
    s = wredsum(s);
    float mu = s*(1.f/512.f);
    float vs = 0.f;
    #pragma unroll
    for (int j=0;j<8;++j){ float d=v[j]-mu; vs+=d*d; }
    vs = wredsum(vs);
    float rsig = rsqrtf(vs*(1.f/512.f)+1e-5f);
    int md = modv[token];
    float xin[8], ss=0.f;
    #pragma unroll
    for (int j=0;j<8;++j){
        int d = (j<<6)+lane;
        float hn = (v[j]-mu)*rsig;
        float xi = md ? hn*(gamma[(b<<9)+d]+1.f)+beta[(b<<9)+d] : hn*(lng[d]+1.f);
        xin[j]=xi; ss+=xi*xi;
    }
    ss = wredsum(ss);
    float fac = 22.62741699796952f / fmaxf(sqrtf(ss), 1e-12f);
    #pragma unroll
    for (int j=0;j<8;++j){
        int d=(j<<6)+lane;
        Y[((size_t)token<<9)+d] = f2bf(xin[j]*fac*(ng[d]+1.f));
    }
}

__global__ __launch_bounds__(256) void k_final(const float* __restrict__ X, const float* __restrict__ g, float* __restrict__ out){
    int token = blockIdx.x*4 + (threadIdx.x>>6);
    int lane = threadIdx.x & 63;
    const float* xr = X + ((size_t)token<<9);
    float v[8], ss=0.f;
    #pragma unroll
    for (int j=0;j<8;++j){ v[j]=xr[(j<<6)+lane]; ss+=v[j]*v[j]; }
    ss=wredsum(ss);
    float fac = 22.62741699796952f / fmaxf(sqrtf(ss),1e-12f);
    #pragma unroll
    for (int j=0;j<8;++j){
        int d=(j<<6)+lane;
        out[((size_t)token<<9)+d] = v[j]*fac*(g[d]+1.f);
    }
}

__global__ void k_act(const US* __restrict__ u, US* __restrict__ act){
    int idx = blockIdx.x*256+threadIdx.x;
    if (idx >= 4096*1376) return;
    int t = idx / 1376, c = idx % 1376;
    float val = 0.f;
    if (c < 1365) {
        float a = bf2f(u[(size_t)t*2816 + c]);
        float g = bf2f(u[(size_t)t*2816 + 1365 + c]);
        val = 0.5f*g*(1.f+erff(g*0.70710678118f)) * a;
    }
    act[idx] = f2bf(val);
}

// ---------------- MFMA GEMM: C(MxN) = A(MxK) @ BT(NxK)^T ; tiles 128xBN, BK=32 ----------------
// global_load_lds staging (m97 pattern), unpadded [row][32k] LDS, ds_read_b128 frags.
// EPI 0: store bf16 C. EPI 1: +bias(f32), store bf16 C.
// EPI 2: gate/scale modulated residual into fp32 X (N==512). EPI 3: +bias then as EPI 2.
template<int BN, int EPI>
__global__ __launch_bounds__(256) void k_gemm(
    const US* __restrict__ A, const US* __restrict__ BT, US* __restrict__ C,
    const float* __restrict__ bias, float* __restrict__ X,
    const float* __restrict__ gate, const float* __restrict__ scale,
    const unsigned char* __restrict__ modv, int M, int N, int K)
{
    constexpr int BM = 128, BK = 32;
    constexpr int NF = BN/32;               // n-frags per wave
    __shared__ US As[BM*BK];
    __shared__ US Bs[BN*BK];
    int tid = threadIdx.x;
    int wave = tid>>6, lane = tid&63, quad = lane>>4, l15 = lane&15;
    int m0 = blockIdx.y*BM, n0 = blockIdx.x*BN;
    int wm = (wave&1)<<6;
    int wn = (wave>>1)*(BN/2);
    f32x4 acc[4][NF];
    #pragma unroll
    for (int i=0;i<4;++i)
        #pragma unroll
        for (int j=0;j<NF;++j) acc[i][j]=(f32x4){0.f,0.f,0.f,0.f};

    const US* gA0 = A  + (size_t)(m0 + (tid>>2))*K + ((tid&3)<<3);
    const US* gA1 = gA0 + (size_t)64*K;
    const US* gB0 = BT + (size_t)(n0 + (tid>>2))*K + ((tid&3)<<3);
    const US* gB1 = gB0 + (size_t)64*K;
    US* lA0 = &As[tid<<3]; US* lA1 = &As[(tid<<3)+2048];
    US* lB0 = &Bs[tid<<3]; US* lB1 = (BN==128)? &Bs[(tid<<3)+2048] : nullptr;

    for (int k0=0; k0<K; k0+=BK){
        __syncthreads();
        gload_lds16(gA0 + k0, lA0);
        gload_lds16(gA1 + k0, lA1);
        gload_lds16(gB0 + k0, lB0);
        if (BN==128) gload_lds16(gB1 + k0, lB1);
        __syncthreads();   // drains vmcnt before any wave proceeds
        short8 af[4], bf[NF];
        #pragma unroll
        for (int i=0;i<4;++i) af[i] = *(const short8*)&As[(wm + (i<<4) + l15)*BK + (quad<<3)];
        #pragma unroll
        for (int j=0;j<NF;++j) bf[j] = *(const short8*)&Bs[(wn + (j<<4) + l15)*BK + (quad<<3)];
        #pragma unroll
        for (int i=0;i<4;++i)
            #pragma unroll
            for (int j=0;j<NF;++j)
                acc[i][j] = __builtin_amdgcn_mfma_f32_16x16x32_bf16(af[i], bf[j], acc[i][j], 0,0,0);
    }
    #pragma unroll
    for (int i=0;i<4;++i){
        #pragma unroll
        for (int j=0;j<NF;++j){
            int col = n0 + wn + (j<<4) + l15;
            #pragma unroll
            for (int r=0;r<4;++r){
                int row = m0 + wm + (i<<4) + (quad<<2) + r;
                float v = acc[i][j][r];
                if (EPI==1 || EPI==3) v += bias[col];
                if (EPI<=1){
                    C[(size_t)row*N + col] = f2bf(v);
                } else {
                    float o = modv[row] ? v*gate[((row>>11)<<9) + col] : v*scale[col];
                    X[((size_t)row<<9) + col] += o;
                }
            }
        }
    }
}

// ---------------- V transpose: qkv V-part -> VT[bh][d(64)][key(2048)] ----------------
__global__ __launch_bounds__(256) void k_vtrans(const US* __restrict__ qkv, US* __restrict__ VT){
    __shared__ US Ts[64*72];
    int bh = blockIdx.y;               // 0..15
    int kt = blockIdx.x;               // 0..31 (64-key tiles)
    int b = bh>>3, h = bh&7;
    int tid = threadIdx.x;
    #pragma unroll
    for (int it=0; it<2; ++it){
        int idx = tid + (it<<8);
        int key = idx>>3, d8 = (idx&7)<<3;
        *(uint4*)&Ts[key*72 + d8] =
            *(const uint4*)(qkv + (size_t)(b*2048 + kt*64 + key)*1536 + 1024 + h*64 + d8);
    }
    __syncthreads();
    #pragma unroll
    for (int it=0; it<2; ++it){
        int oidx = tid + (it<<8);
        int d = oidx>>3, kb = (oidx&7)<<3;
        US tmp[8];
        #pragma unroll
        for (int j=0;j<8;++j) tmp[j] = Ts[(kb+j)*72 + d];
        *(uint4*)(VT + (size_t)bh*131072 + (size_t)d*2048 + kt*64 + kb) = *(uint4*)tmp;
    }
}

// ---------------- MFMA flash attention, causal, softcap 50 ----------------
__global__ __launch_bounds__(256) void k_attn(const US* __restrict__ qkv, const US* __restrict__ VT,
                                              US* __restrict__ O)
{
    int blk = blockIdx.x;              // 256
    int bh = blk >> 4, p = blk & 15;
    int b = bh >> 3, h = bh & 7;
    int tid = threadIdx.x, wave = tid>>6, lane = tid&63, quad = lane>>4, l15 = lane&15;
    __shared__ US Ks[64*72];
    __shared__ US Vt[64*72];
    __shared__ US Ps[4*16*72];
    US* ps = Ps + wave*16*72;

    int skey0 = tid>>3,  soff0 = (tid&7)<<3;
    const US* Kg = qkv + (size_t)(b*2048)*1536 + 512 + h*64;
    const US* Vg = VT + (size_t)bh*131072;

    int rbs[2] = {p, 31-p};
    #pragma unroll
    for (int ti=0; ti<2; ++ti){
        int rb = rbs[ti];
        int qrow0 = (rb<<6) + (wave<<4);
        const US* qbase = qkv + (size_t)(b*2048 + qrow0 + l15)*1536 + h*64 + (quad<<3);
        short8 qf0 = *(const short8*)qbase;
        short8 qf1 = *(const short8*)(qbase + 32);
        f32x4 Oa[4];
        #pragma unroll
        for (int nb=0;nb<4;++nb) Oa[nb]=(f32x4){0.f,0.f,0.f,0.f};
        float lsum[4] = {0.f,0.f,0.f,0.f};

        uint4 ka0 = *(const uint4*)(Kg + (size_t)(skey0)*1536 + soff0);
        uint4 ka1 = *(const uint4*)(Kg + (size_t)(skey0+32)*1536 + soff0);
        uint4 va0 = *(const uint4*)(Vg + (size_t)(skey0)*2048 + soff0);
        uint4 va1 = *(const uint4*)(Vg + (size_t)(skey0+32)*2048 + soff0);

        for (int c=0; c<=rb; ++c){
            int j0 = c<<6;
            __syncthreads();
            *(uint4*)&Ks[skey0*72 + soff0]      = ka0;
            *(uint4*)&Ks[(skey0+32)*72 + soff0] = ka1;
            *(uint4*)&Vt[skey0*72 + soff0]      = va0;
            *(uint4*)&Vt[(skey0+32)*72 + soff0] = va1;
            __syncthreads();
            if (c < rb){
                int j1 = j0 + 64;
                ka0 = *(const uint4*)(Kg + (size_t)(j1+skey0)*1536 + soff0);
                ka1 = *(const uint4*)(Kg + (size_t)(j1+skey0+32)*1536 + soff0);
                va0 = *(const uint4*)(Vg + (size_t)(skey0)*2048 + j1 + soff0);
                va1 = *(const uint4*)(Vg + (size_t)(skey0+32)*2048 + j1 + soff0);
            }
            f32x4 s[4];
            #pragma unroll
            for (int nb=0;nb<4;++nb){
                s[nb]=(f32x4){0.f,0.f,0.f,0.f};
                short8 kf0 = *(const short8*)&Ks[((nb<<4)+l15)*72 + (quad<<3)];
                short8 kf1 = *(const short8*)&Ks[((nb<<4)+l15)*72 + 32 + (quad<<3)];
                s[nb] = __builtin_amdgcn_mfma_f32_16x16x32_bf16(qf0, kf0, s[nb],0,0,0);
                s[nb] = __builtin_amdgcn_mfma_f32_16x16x32_bf16(qf1, kf1, s[nb],0,0,0);
            }
            int diag = (c==rb);
            #pragma unroll
            for (int nb=0;nb<4;++nb){
                int grp = (nb<<1) + (l15>>3);
                #pragma unroll
                for (int r=0;r<4;++r){
                    float e2 = __expf(s[nb][r]*0.005f);
                    float t = 1.f - 2.f*fastrcp(e2+1.f);
                    float pv = __expf(50.f*t);
                    if (diag){
                        int key = j0 + (nb<<4) + l15;
                        int rowg = qrow0 + (quad<<2) + r;
                        if (key > rowg) pv = 0.f;
                    }
                    lsum[r] += pv;
                    ps[((quad<<2)+r)*72 + ((grp^r)<<3) + (l15&7)] = f2bf(pv);
                }
            }
            int gs0 = quad ^ (l15&3);
            int gs1 = (4+quad) ^ (l15&3);
            short8 pf0 = *(const short8*)&ps[l15*72 + (gs0<<3)];
            short8 pf1 = *(const short8*)&ps[l15*72 + (gs1<<3)];
            #pragma unroll
            for (int nb=0;nb<4;++nb){
                short8 vf0 = *(const short8*)&Vt[((nb<<4)+l15)*72 + (quad<<3)];
                short8 vf1 = *(const short8*)&Vt[((nb<<4)+l15)*72 + 32 + (quad<<3)];
                Oa[nb] = __builtin_amdgcn_mfma_f32_16x16x32_bf16(pf0, vf0, Oa[nb],0,0,0);
                Oa[nb] = __builtin_amdgcn_mfma_f32_16x16x32_bf16(pf1, vf1, Oa[nb],0,0,0);
            }
        }
        float inv[4];
        #pragma unroll
        for (int r=0;r<4;++r){
            float v = lsum[r];
            v += __shfl_xor(v,1); v += __shfl_xor(v,2);
            v += __shfl_xor(v,4); v += __shfl_xor(v,8);
            inv[r] = 1.f / fmaxf(v, 1e-30f);
        }
        #pragma unroll
        for (int nb=0;nb<4;++nb){
            #pragma unroll
            for (int r=0;r<4;++r){
                int rowg = qrow0 + (quad<<2) + r;
                O[(size_t)(b*2048+rowg)*512 + h*64 + (nb<<4) + l15] = f2bf(Oa[nb][r]*inv[r]);
            }
        }
    }
}

// ---------------- launcher ----------------
extern "C" void kernel_launch(void* const* d_in, const int* in_sizes, int n_in,
                              void* d_out, int out_size, void* d_ws, size_t ws_size,
                              hipStream_t stream)
{
    (void)in_sizes; (void)n_in; (void)out_size; (void)ws_size;
    const float* x        = (const float*)d_in[0];
    const float* times    = (const float*)d_in[1];
    const int*   mod_raw  = (const int*)d_in[3];   // attn_mask (d_in[2]) = causal tril, hardcoded
    const float* fourier  = (const float*)d_in[4];
    const float* time_w   = (const float*)d_in[5];
    const float* time_b   = (const float*)d_in[6];
    const float* aw_ln_g  = (const float*)d_in[7];
    const float* aw_scale = (const float*)d_in[8];
    const float* aw_film_w= (const float*)d_in[9];
    const float* aw_film_b= (const float*)d_in[10];
    const float* aw_zero_w= (const float*)d_in[11];
    const float* aw_zero_b= (const float*)d_in[12];
    const float* attn_norm_g=(const float*)d_in[13];
    const float* qkv_w    = (const float*)d_in[14];
    const float* out_w    = (const float*)d_in[15];
    const float* fw_ln_g  = (const float*)d_in[16];
    const float* fw_scale = (const float*)d_in[17];
    const float* fw_film_w= (const float*)d_in[18];
    const float* fw_film_b= (const float*)d_in[19];
    const float* fw_zero_w= (const float*)d_in[20];
    const float* fw_zero_b= (const float*)d_in[21];
    const float* ff_norm_g= (const float*)d_in[22];
    const float* ff_w1    = (const float*)d_in[23];
    const float* ff_b1    = (const float*)d_in[24];
    const float* ff_w2    = (const float*)d_in[25];
    const float* ff_b2    = (const float*)d_in[26];
    const float* final_g  = (const float*)d_in[27];

    char* ws = (char*)d_ws;
    size_t off = 0;
    auto alloc = [&](size_t bytes)->char*{ char* p = ws+off; off += (bytes + 255) & ~(size_t)255; return p; };
    float* Xf   = (float*)alloc(4096ull*512*4);
    US* Y       = (US*)alloc(4096ull*512*2);
    US* QKV     = (US*)alloc(4096ull*1536*2);
    US* VT      = (US*)alloc(16ull*64*2048*2);
    US* Ob      = (US*)alloc(4096ull*512*2);
    US* U       = (US*)alloc(4096ull*2816*2);
    US* ACT     = (US*)alloc(4096ull*1376*2);
    US* QWT     = (US*)alloc(4ull*1536*512*2);   // [l][n=1536][k=512]
    US* OWT     = (US*)alloc(4ull*512*512*2);    // [l][n=512][k=512]
    US* W1T     = (US*)alloc(4ull*2816*512*2);   // [l][n=2816][k=512]
    float* B1P  = (float*)alloc(4ull*2816*4);
    US* W2T     = (US*)alloc(4ull*512*1376*2);   // [l][n=512][k=1376]
    float* FEMB = (float*)alloc(2*513*4);
    float* CACC = (float*)alloc(4096*4);
    float* COND = (float*)alloc(2*2048*4);
    float* FACC = (float*)alloc(24576*4);
    float* GAM  = (float*)alloc(8192*4);   // [lt(4x2)][b][512]
    float* BET  = (float*)alloc(8192*4);
    float* GATE = (float*)alloc(8192*4);
    unsigned char* MOD = (unsigned char*)alloc(4096);
    int* FLAG   = (int*)alloc(256);

    k_copy<<<8192,256,0,stream>>>(x, Xf, 4096*512);
    k_detect<<<1,256,0,stream>>>(mod_raw, FLAG);
    k_mod<<<16,256,0,stream>>>(mod_raw, FLAG, MOD);
    // weight transposes: dst[n][k] = src[k][n]
    k_wt<<<dim3(8,24,4),256,0,stream>>>(qkv_w, QWT, 512,1536, 512,1536);
    k_wt<<<dim3(8,8,4),256,0,stream>>>(out_w, OWT, 512,512, 512,512);
    k_wt<<<dim3(8,44,4),256,0,stream>>>(ff_w1, W1T, 512,2730, 512,2816);
    k_wt<<<dim3(22,8,4),256,0,stream>>>(ff_w2, W2T, 1365,512, 1376,512);
    k_padb1<<<(4*2816+255)/256,256,0,stream>>>(ff_b1, B1P);
    k_femb<<<5,256,0,stream>>>(times, fourier, FEMB);
    hipMemsetAsync(CACC, 0, 4096*4, stream);
    k_cond1<<<64,256,0,stream>>>(FEMB, time_w, CACC);
    k_condfin<<<16,256,0,stream>>>(CACC, time_b, COND);
    hipMemsetAsync(FACC, 0, 24576*4, stream);
    k_film2f<<<256,256,0,stream>>>(COND, aw_film_w, fw_film_w, FACC);
    k_film2z<<<256,256,0,stream>>>(COND, aw_zero_w, fw_zero_w, FACC);
    k_filmfin<<<96,256,0,stream>>>(FACC, aw_film_b, aw_zero_b, fw_film_b, fw_zero_b, GAM, BET, GATE);

    for (int l=0;l<4;++l){
        int lt0 = (l*2+0)*1024, lt1 = (l*2+1)*1024;
        // ---- attention block ----
        k_normmod<<<1024,256,0,stream>>>(Xf, GAM+lt0, BET+lt0, aw_ln_g + l*512, attn_norm_g + l*512, MOD, Y);
        k_gemm<128,0><<<dim3(12,32),256,0,stream>>>(Y, QWT + (size_t)l*1536*512, QKV,
                    nullptr, nullptr, nullptr, nullptr, nullptr, 4096,1536,512);
        k_vtrans<<<dim3(32,16),256,0,stream>>>(QKV, VT);
        k_attn<<<256,256,0,stream>>>(QKV, VT, Ob);
        k_gemm<64,2><<<dim3(8,32),256,0,stream>>>(Ob, OWT + (size_t)l*512*512, nullptr,
                    nullptr, Xf, GATE+lt0, aw_scale + l*512, MOD, 4096,512,512);
        // ---- feed-forward block ----
        k_normmod<<<1024,256,0,stream>>>(Xf, GAM+lt1, BET+lt1, fw_ln_g + l*512, ff_norm_g + l*512, MOD, Y);
        k_gemm<128,1><<<dim3(22,32),256,0,stream>>>(Y, W1T + (size_t)l*2816*512, U,
                    B1P + l*2816, nullptr, nullptr, nullptr, nullptr, 4096,2816,512);
        k_act<<<(4096*1376+255)/256,256,0,stream>>>(U, ACT);
        k_gemm<64,3><<<dim3(8,32),256,0,stream>>>(ACT, W2T + (size_t)l*512*1376, nullptr,
                    ff_b2 + l*512, Xf, GATE+lt1, fw_scale + l*512, MOD, 4096,512,1376);
    }
    k_final<<<1024,256,0,stream>>>(Xf, final_g, (float*)d_out);
}